// Round 7
// baseline (255.239 us; speedup 1.0000x reference)
//
#include <hip/hip_runtime.h>

#define NNODES 50000
#define NEDGES 1600000
#define NB 196        // buckets = dst>>8  (50000/256 -> 0..195)
#define BCAP 10240    // edges per bucket capacity (mean 8163, +20 sigma)

typedef __attribute__((ext_vector_type(8))) short short8;   // 8 x bf16
typedef __attribute__((ext_vector_type(4))) float fp32x4;   // MFMA C/D frag

__device__ __forceinline__ unsigned short f2bf(float f) {   // RNE fp32 -> bf16
    unsigned int u = __float_as_uint(f);
    u += 0x7fffu + ((u >> 16) & 1u);
    return (unsigned short)(u >> 16);
}
__device__ __forceinline__ float bflo(unsigned int p) { return __uint_as_float(p << 16); }
__device__ __forceinline__ float bfhi(unsigned int p) { return __uint_as_float(p & 0xffff0000u); }

// signed-byte j of dword u -> float (v_bfe_i32 + v_cvt_f32_i32)
__device__ __forceinline__ float sb2f(unsigned int u, int j) {
    return (float)((int)(u << (24 - 8 * j)) >> 24);
}

// ---------------------------------------------------------------------------
// Cast + transpose W (128x128 fp32, k-major) -> WT bf16 (n-major).
// Also zeroes gcur (replaces a memset dispatch; runs before pass1 in-stream).
// ---------------------------------------------------------------------------
__global__ __launch_bounds__(128) void cast_wt(
    const float* __restrict__ WQ, const float* __restrict__ WK,
    const float* __restrict__ WV, unsigned short* __restrict__ WT,
    int* __restrict__ gcur)
{
    if (blockIdx.x == 0) {
        gcur[threadIdx.x] = 0;
        gcur[threadIdx.x + 128] = 0;
    }
    const int w = blockIdx.x >> 7;
    const int n = blockIdx.x & 127;
    const int k = threadIdx.x;
    const float* W = (w == 0) ? WQ : ((w == 1) ? WK : WV);
    WT[w * 16384 + n * 128 + k] = f2bf(W[k * 128 + n]);
}

// ---------------------------------------------------------------------------
// Fused QKV projection, bf16 MFMA 16x16x32. Outputs:
//   Qb  [n][128] bf16 (unchanged)
//   KVb [n][256] BYTES: [K int8 128B | V int8 128B]  -- 2 cache lines/row
//   scl [n][8] float2: per-(node,head) {kscale, vscale}. kscale folds the
//     1/sqrt(16) score scale (kmax/(127*4)); vscale = vmax/127.
// Verified in round 6 (absmax 0.03125).
// ---------------------------------------------------------------------------
__global__ __launch_bounds__(256) void proj_mfma(
    const float* __restrict__ state, const unsigned short* __restrict__ WT,
    const float* __restrict__ bQ, const float* __restrict__ bK,
    const float* __restrict__ bV,
    unsigned short* __restrict__ Qb, unsigned char* __restrict__ KVb,
    float* __restrict__ scl)
{
    __shared__ float lbuf[4][16 * 132];

    const int tid  = threadIdx.x;
    const int wv   = tid >> 6;
    const int lane = tid & 63;
    const int lm   = lane & 15;    // A row / B col / C col within tile
    const int quad = lane >> 4;    // k-chunk select, C row group
    const int m0   = blockIdx.x * 64 + wv * 16;
    const int m    = m0 + lm;

    fp32x4 acc[3][8];
#pragma unroll
    for (int w = 0; w < 3; ++w)
#pragma unroll
        for (int t = 0; t < 8; ++t)
            acc[w][t] = (fp32x4){0.f, 0.f, 0.f, 0.f};

    const int kq = quad * 8;
#pragma unroll
    for (int kb = 0; kb < 128; kb += 32) {
        short8 a = (short8){0,0,0,0,0,0,0,0};
        if (m < NNODES) {
            const float4 f0 = *(const float4*)(state + (size_t)m * 128 + kb + kq);
            const float4 f1 = *(const float4*)(state + (size_t)m * 128 + kb + kq + 4);
            a[0] = (short)f2bf(f0.x); a[1] = (short)f2bf(f0.y);
            a[2] = (short)f2bf(f0.z); a[3] = (short)f2bf(f0.w);
            a[4] = (short)f2bf(f1.x); a[5] = (short)f2bf(f1.y);
            a[6] = (short)f2bf(f1.z); a[7] = (short)f2bf(f1.w);
        }
#pragma unroll
        for (int w = 0; w < 3; ++w) {
#pragma unroll
            for (int t = 0; t < 8; ++t) {
                const short8 b = *(const short8*)(WT + w * 16384 + (t * 16 + lm) * 128 + kb + kq);
                acc[w][t] = __builtin_amdgcn_mfma_f32_16x16x32_bf16(a, b, acc[w][t], 0, 0, 0);
            }
        }
    }

    const int rrow = lane >> 2;          // 0..15
    const int rcol = (lane & 3) * 32;    // 0,32,64,96 -> heads h0=(lane&3)*2, h0+1
    const int h0   = (lane & 3) * 2;
    const int grow = m0 + rrow;
#pragma unroll
    for (int w = 0; w < 3; ++w) {
        const float* bp = (w == 0) ? bQ : ((w == 1) ? bK : bV);
        float* L = &lbuf[wv][0];
#pragma unroll
        for (int t = 0; t < 8; ++t) {
            const float bb = bp[t * 16 + lm];
#pragma unroll
            for (int r = 0; r < 4; ++r)
                L[(quad * 4 + r) * 132 + t * 16 + lm] = acc[w][t][r] + bb;
        }
        __syncthreads();
        if (grow < NNODES) {
            float xv[32];
#pragma unroll
            for (int c = 0; c < 4; ++c) {
                const float* lp = &L[rrow * 132 + rcol + c * 8];   // 16B aligned
                const float4 x0 = *(const float4*)(lp);
                const float4 x1 = *(const float4*)(lp + 4);
                xv[c*8+0] = x0.x; xv[c*8+1] = x0.y; xv[c*8+2] = x0.z; xv[c*8+3] = x0.w;
                xv[c*8+4] = x1.x; xv[c*8+5] = x1.y; xv[c*8+6] = x1.z; xv[c*8+7] = x1.w;
            }
            if (w == 0) {
                unsigned short* gp = Qb + (size_t)grow * 128 + rcol;
#pragma unroll
                for (int c = 0; c < 4; ++c) {
                    short8 r;
#pragma unroll
                    for (int j = 0; j < 8; ++j) r[j] = (short)f2bf(xv[c*8+j]);
                    *(short8*)(gp + c * 8) = r;
                }
            } else {
                // int8 per-head symmetric quantization (2 heads per thread)
#pragma unroll
                for (int g = 0; g < 2; ++g) {
                    const int b = g * 16;
                    float mx = 0.f;
#pragma unroll
                    for (int j = 0; j < 16; ++j) mx = fmaxf(mx, fabsf(xv[b + j]));
                    const float inv = (mx > 0.f) ? 127.0f / mx : 0.f;
                    unsigned int du[4];
#pragma unroll
                    for (int d = 0; d < 4; ++d) {
                        const int b0 = (int)rintf(xv[b + d*4 + 0] * inv);
                        const int b1 = (int)rintf(xv[b + d*4 + 1] * inv);
                        const int b2 = (int)rintf(xv[b + d*4 + 2] * inv);
                        const int b3 = (int)rintf(xv[b + d*4 + 3] * inv);
                        du[d] = (unsigned)(b0 & 255) | ((unsigned)(b1 & 255) << 8)
                              | ((unsigned)(b2 & 255) << 16) | ((unsigned)(b3 & 255) << 24);
                    }
                    const int h = h0 + g;
                    unsigned char* gp = KVb + (size_t)grow * 256 + ((w == 1) ? 0 : 128) + h * 16;
                    *(uint4*)gp = (uint4){du[0], du[1], du[2], du[3]};
                    // scales: K -> .x (folds 0.25), V -> .y
                    if (w == 1) scl[((size_t)grow * 8 + h) * 2 + 0] = mx * (1.0f / 508.0f);
                    else        scl[((size_t)grow * 8 + h) * 2 + 1] = mx * (1.0f / 127.0f);
                }
            }
        }
        __syncthreads();
    }
}

// ---------------------------------------------------------------------------
// Counting-sort pass 1 (packed word (bucket<<24|src<<8|dstlow), wave shfl_up
// scan). Verified in round 5.
// ---------------------------------------------------------------------------
__global__ __launch_bounds__(256) void bucket_pass1(
    const int* __restrict__ src, const int* __restrict__ dst,
    int* __restrict__ gcur, int* __restrict__ pbuf)
{
    __shared__ int hist[256];
    __shared__ int lofs[256];
    __shared__ int gbase[256];
    __shared__ int wsum[4];
    __shared__ int pktg[2048];

    const int t = threadIdx.x;
    hist[t] = 0;
    __syncthreads();

    const long long e0 = (long long)blockIdx.x * 2048 + t * 8;
    const bool valid = (e0 < NEDGES);
    unsigned int w8[8]; int b8[8], r8[8];
    if (valid) {
        const int4 sA = *(const int4*)(src + e0);
        const int4 sB = *(const int4*)(src + e0 + 4);
        const int4 dA = *(const int4*)(dst + e0);
        const int4 dB = *(const int4*)(dst + e0 + 4);
        const int dd[8] = {dA.x, dA.y, dA.z, dA.w, dB.x, dB.y, dB.z, dB.w};
        const int ss[8] = {sA.x, sA.y, sA.z, sA.w, sB.x, sB.y, sB.z, sB.w};
#pragma unroll
        for (int j = 0; j < 8; ++j) {
            const int bb = dd[j] >> 8;
            b8[j] = bb;
            w8[j] = ((unsigned)bb << 24) | ((unsigned)ss[j] << 8) | (unsigned)(dd[j] & 255);
            r8[j] = atomicAdd(&hist[bb], 1);
        }
    }
    __syncthreads();

    const int v = hist[t];
    if (t < NB && v > 0) gbase[t] = atomicAdd(&gcur[t], v);

    int x = v;
#pragma unroll
    for (int off = 1; off < 64; off <<= 1) {
        const int y = __shfl_up(x, off);
        if ((t & 63) >= off) x += y;
    }
    if ((t & 63) == 63) wsum[t >> 6] = x;
    __syncthreads();
    int pre = 0;
#pragma unroll
    for (int ww = 0; ww < 4; ++ww)
        if (ww < (t >> 6)) pre += wsum[ww];
    const int tot = wsum[0] + wsum[1] + wsum[2] + wsum[3];
    lofs[t] = x + pre - v;          // exclusive prefix
    __syncthreads();

    if (valid) {
#pragma unroll
        for (int j = 0; j < 8; ++j)
            pktg[lofs[b8[j]] + r8[j]] = (int)w8[j];
    }
    __syncthreads();

#pragma unroll
    for (int j = 0; j < 8; ++j) {
        const int slot = t + 256 * j;
        if (slot < tot) {
            const unsigned int w = (unsigned int)pktg[slot];
            const int bb = (int)(w >> 24);
            const long long g = (long long)bb * BCAP + gbase[bb] + (slot - lofs[bb]);
            pbuf[g] = (int)(w & 0x00FFFFFFu);
        }
    }
}

// ---------------------------------------------------------------------------
// Counting-sort pass 2: one block per bucket, 1024 threads, packed word,
// wave shfl_up scan. Verified in round 5.
// ---------------------------------------------------------------------------
__global__ __launch_bounds__(1024) void bucket_pass2(
    const int* __restrict__ pbuf, const int* __restrict__ gcur,
    int* __restrict__ eidx, int2* __restrict__ offs2)
{
    __shared__ int hist[256];
    __shared__ int cur[256];
    __shared__ int wsum[4];
    __shared__ int pstash[BCAP];    // 40 KB packed words
    __shared__ int srcbuf[BCAP];    // 40 KB grouped src ids

    const int b = blockIdx.x;
    const int t = threadIdx.x;
    int cnt = gcur[b];
    if (cnt > BCAP) cnt = BCAP;
    const long long base = (long long)b * BCAP;

    if (t < 256) hist[t] = 0;
    __syncthreads();

    for (int i = t; i < cnt; i += 1024) {
        const int g = pbuf[base + i];
        pstash[i] = g;
        atomicAdd(&hist[g & 255], 1);
    }
    __syncthreads();

    int x = 0, v = 0;
    if (t < 256) {
        v = hist[t];
        x = v;
#pragma unroll
        for (int off = 1; off < 64; off <<= 1) {
            const int y = __shfl_up(x, off);
            if ((t & 63) >= off) x += y;
        }
        if ((t & 63) == 63) wsum[t >> 6] = x;
    }
    __syncthreads();
    if (t < 256) {
        int pre = 0;
#pragma unroll
        for (int ww = 0; ww < 4; ++ww)
            if (ww < (t >> 6)) pre += wsum[ww];
        const int ex = x + pre - v;          // exclusive
        cur[t] = ex;
        const int n = b * 256 + t;
        if (n < NNODES) {
            int2 oe; oe.x = (int)(base + ex); oe.y = (int)(base + ex + v);
            offs2[n] = oe;
        }
    }
    __syncthreads();

    for (int i = t; i < cnt; i += 1024) {
        const int g = pstash[i];
        const int p = atomicAdd(&cur[g & 255], 1);
        srcbuf[p] = g >> 8;
    }
    __syncthreads();

    for (int i = t; i < cnt; i += 1024)
        eidx[base + i] = srcbuf[i];
}

// ---------------------------------------------------------------------------
// Aggregation: one wave per dst node; lane = (edge-slot eo=l>>3, head h=l&7).
// Round-7: warm-iteration rows (FETCH~0, same 79.8us) prove this kernel is
// L2/L3-latency-bound, NOT bandwidth-bound (5.1 TB/s cache-side vs 34.5
// ceiling; VALU 52%; 3.34 TB/s < the 3.74 plateau -> miss queue not full).
// Lever: 4 edges/lane (32/iter) with all 12 gathers (4K+4V+4scl) issued
// before any decode -- double the in-flight loads per wave (Little's law).
// Masked slots alias eidx[beg]: all masked lanes hit the same row (2 lines).
// ---------------------------------------------------------------------------
__global__ __launch_bounds__(256) void aggregate_kernel(
    const int* __restrict__ eidx, const int2* __restrict__ offs2,
    const unsigned short* __restrict__ Qb, const unsigned char* __restrict__ KVb,
    const float* __restrict__ scl, float* __restrict__ out)
{
    const int n = blockIdx.x * 4 + (threadIdx.x >> 6);
    const int l = threadIdx.x & 63;
    if (n >= NNODES) return;
    const int eo = l >> 3;       // edge slot 0..7
    const int h  = l & 7;        // head 0..7

    const unsigned short* qp = Qb + (size_t)n * 128 + h * 16;
    const uint4 qa = *(const uint4*)(qp);
    const uint4 qc = *(const uint4*)(qp + 8);
    float q[16];
    q[0]  = bflo(qa.x); q[1]  = bfhi(qa.x); q[2]  = bflo(qa.y); q[3]  = bfhi(qa.y);
    q[4]  = bflo(qa.z); q[5]  = bfhi(qa.z); q[6]  = bflo(qa.w); q[7]  = bfhi(qa.w);
    q[8]  = bflo(qc.x); q[9]  = bfhi(qc.x); q[10] = bflo(qc.y); q[11] = bfhi(qc.y);
    q[12] = bflo(qc.z); q[13] = bfhi(qc.z); q[14] = bflo(qc.w); q[15] = bfhi(qc.w);

    const int2 oe = offs2[n];
    const int beg = oe.x, end = oe.y;

    float acc[16];
#pragma unroll
    for (int j = 0; j < 16; ++j) acc[j] = 0.f;
    float zacc = 0.f;

    for (int i = beg; i < end; i += 32) {
        // --- issue all index gathers ---
        int s[4]; bool act[4];
#pragma unroll
        for (int u = 0; u < 4; ++u) {
            const int ei = i + eo + u * 8;
            act[u] = (ei < end);
            s[u] = eidx[act[u] ? ei : beg];
        }
        // --- issue all 12 row/scale gathers before any decode ---
        uint4 kw[4], vw[4]; float2 sc[4];
#pragma unroll
        for (int u = 0; u < 4; ++u) {
            const unsigned char* rp = KVb + (size_t)s[u] * 256;
            kw[u] = *(const uint4*)(rp + h * 16);
            vw[u] = *(const uint4*)(rp + 128 + h * 16);
            sc[u] = *(const float2*)(scl + ((size_t)s[u] * 8 + h) * 2);
        }

        float w[4];
#pragma unroll
        for (int u = 0; u < 4; ++u) {
            float p;
            p = sb2f(kw[u].x, 0) * q[0];
            p = fmaf(sb2f(kw[u].x, 1), q[1],  p); p = fmaf(sb2f(kw[u].x, 2), q[2],  p);
            p = fmaf(sb2f(kw[u].x, 3), q[3],  p); p = fmaf(sb2f(kw[u].y, 0), q[4],  p);
            p = fmaf(sb2f(kw[u].y, 1), q[5],  p); p = fmaf(sb2f(kw[u].y, 2), q[6],  p);
            p = fmaf(sb2f(kw[u].y, 3), q[7],  p); p = fmaf(sb2f(kw[u].z, 0), q[8],  p);
            p = fmaf(sb2f(kw[u].z, 1), q[9],  p); p = fmaf(sb2f(kw[u].z, 2), q[10], p);
            p = fmaf(sb2f(kw[u].z, 3), q[11], p); p = fmaf(sb2f(kw[u].w, 0), q[12], p);
            p = fmaf(sb2f(kw[u].w, 1), q[13], p); p = fmaf(sb2f(kw[u].w, 2), q[14], p);
            p = fmaf(sb2f(kw[u].w, 3), q[15], p);
            p *= sc[u].x;                    // kmax/(127*4): dequant + 1/sqrt(D)
            float ww = __expf(fminf(fmaxf(p, -5.f), 5.f));
            ww = act[u] ? ww : 0.f;
            zacc += ww;
            w[u] = ww * sc[u].y;             // fold vscale into the weight
        }

#pragma unroll
        for (int u = 0; u < 4; ++u) {
            const float wv = w[u];
            acc[0]  = fmaf(sb2f(vw[u].x, 0), wv, acc[0]);  acc[1]  = fmaf(sb2f(vw[u].x, 1), wv, acc[1]);
            acc[2]  = fmaf(sb2f(vw[u].x, 2), wv, acc[2]);  acc[3]  = fmaf(sb2f(vw[u].x, 3), wv, acc[3]);
            acc[4]  = fmaf(sb2f(vw[u].y, 0), wv, acc[4]);  acc[5]  = fmaf(sb2f(vw[u].y, 1), wv, acc[5]);
            acc[6]  = fmaf(sb2f(vw[u].y, 2), wv, acc[6]);  acc[7]  = fmaf(sb2f(vw[u].y, 3), wv, acc[7]);
            acc[8]  = fmaf(sb2f(vw[u].z, 0), wv, acc[8]);  acc[9]  = fmaf(sb2f(vw[u].z, 1), wv, acc[9]);
            acc[10] = fmaf(sb2f(vw[u].z, 2), wv, acc[10]); acc[11] = fmaf(sb2f(vw[u].z, 3), wv, acc[11]);
            acc[12] = fmaf(sb2f(vw[u].w, 0), wv, acc[12]); acc[13] = fmaf(sb2f(vw[u].w, 1), wv, acc[13]);
            acc[14] = fmaf(sb2f(vw[u].w, 2), wv, acc[14]); acc[15] = fmaf(sb2f(vw[u].w, 3), wv, acc[15]);
        }
    }

    // reduce across edge slots (lanes differing in bits 3..5)
#pragma unroll
    for (int st = 8; st < 64; st <<= 1) {
        zacc += __shfl_xor(zacc, st);
#pragma unroll
        for (int j = 0; j < 16; ++j) acc[j] += __shfl_xor(acc[j], st);
    }

    if (eo == 0) {
        const float inv = 1.0f / zacc;
        float* op = out + (size_t)n * 128 + h * 16;
        *(float4*)(op)      = make_float4(acc[0]*inv,  acc[1]*inv,  acc[2]*inv,  acc[3]*inv);
        *(float4*)(op + 4)  = make_float4(acc[4]*inv,  acc[5]*inv,  acc[6]*inv,  acc[7]*inv);
        *(float4*)(op + 8)  = make_float4(acc[8]*inv,  acc[9]*inv,  acc[10]*inv, acc[11]*inv);
        *(float4*)(op + 12) = make_float4(acc[12]*inv, acc[13]*inv, acc[14]*inv, acc[15]*inv);
    }
}

extern "C" void kernel_launch(void* const* d_in, const int* in_sizes, int n_in,
                              void* d_out, int out_size, void* d_ws, size_t ws_size,
                              hipStream_t stream)
{
    const float* state = (const float*)d_in[0];
    const int*   src   = (const int*)d_in[1];
    const int*   dst   = (const int*)d_in[2];
    const float* WQ    = (const float*)d_in[3];
    const float* bQ    = (const float*)d_in[4];
    const float* WK    = (const float*)d_in[5];
    const float* bK    = (const float*)d_in[6];
    const float* WV    = (const float*)d_in[7];
    const float* bV    = (const float*)d_in[8];
    float* out = (float*)d_out;

    unsigned short* Qb  = (unsigned short*)d_ws;                        // 12.8 MB
    unsigned char*  KVb = (unsigned char*)(Qb + (size_t)NNODES * 128);  // 12.8 MB
    float*          scl = (float*)(KVb + (size_t)NNODES * 256);         // 3.2 MB
    unsigned short* WT  = (unsigned short*)(scl + (size_t)NNODES * 16); // 96 KB
    int* pbuf  = (int*)(WT + 3 * 16384);                                // NB*BCAP*4B
    int* eidx  = pbuf + (size_t)NB * BCAP;
    int* gcur  = eidx + (size_t)NB * BCAP;                              // 256
    int2* offs2 = (int2*)(gcur + 256);                                  // 50000 int2

    cast_wt<<<3 * 128, 128, 0, stream>>>(WQ, WK, WV, WT, gcur);
    proj_mfma<<<(NNODES + 63) / 64, 256, 0, stream>>>(state, WT, bQ, bK, bV, Qb, KVb, scl);

    bucket_pass1<<<(NEDGES + 2047) / 2048, 256, 0, stream>>>(src, dst, gcur, pbuf);
    bucket_pass2<<<NB, 1024, 0, stream>>>(pbuf, gcur, eidx, offs2);

    aggregate_kernel<<<(NNODES + 3) / 4, 256, 0, stream>>>(eidx, offs2, Qb, KVb, scl, out);
}

// Round 8
// 242.218 us; speedup vs baseline: 1.0538x; 1.0538x over previous
//
#include <hip/hip_runtime.h>

#define NNODES 50000
#define NEDGES 1600000
#define NB 196        // buckets = dst>>8  (50000/256 -> 0..195)
#define BCAP 10240    // edges per bucket capacity (mean 8163, +20 sigma)

typedef __attribute__((ext_vector_type(8))) short short8;   // 8 x bf16
typedef __attribute__((ext_vector_type(4))) float fp32x4;   // MFMA C/D frag

__device__ __forceinline__ unsigned short f2bf(float f) {   // RNE fp32 -> bf16
    unsigned int u = __float_as_uint(f);
    u += 0x7fffu + ((u >> 16) & 1u);
    return (unsigned short)(u >> 16);
}
__device__ __forceinline__ float bflo(unsigned int p) { return __uint_as_float(p << 16); }
__device__ __forceinline__ float bfhi(unsigned int p) { return __uint_as_float(p & 0xffff0000u); }

// signed-byte j of dword u -> float (v_bfe_i32 + v_cvt_f32_i32)
__device__ __forceinline__ float sb2f(unsigned int u, int j) {
    return (float)((int)(u << (24 - 8 * j)) >> 24);
}

// ---------------------------------------------------------------------------
// Cast + transpose W (128x128 fp32, k-major) -> WT bf16 (n-major).
// Also zeroes gcur (replaces a memset dispatch; runs before pass1 in-stream).
// ---------------------------------------------------------------------------
__global__ __launch_bounds__(128) void cast_wt(
    const float* __restrict__ WQ, const float* __restrict__ WK,
    const float* __restrict__ WV, unsigned short* __restrict__ WT,
    int* __restrict__ gcur)
{
    if (blockIdx.x == 0) {
        gcur[threadIdx.x] = 0;
        gcur[threadIdx.x + 128] = 0;
    }
    const int w = blockIdx.x >> 7;
    const int n = blockIdx.x & 127;
    const int k = threadIdx.x;
    const float* W = (w == 0) ? WQ : ((w == 1) ? WK : WV);
    WT[w * 16384 + n * 128 + k] = f2bf(W[k * 128 + n]);
}

// ---------------------------------------------------------------------------
// Fused QKV projection, bf16 MFMA 16x16x32. Outputs:
//   Qb  [n][128] bf16 (unchanged)
//   KVb [n][256] BYTES: [K int8 128B | V int8 128B]  -- 2 cache lines/row
//   scl [n] float2 {kscale, vscale}: per-NODE scales (round-8: was per-head
//     3.2MB; per-node = 400KB -> L2-resident, and the aggregate's scale
//     gather becomes a same-address broadcast). kscale folds 1/sqrt(16).
// Row max computed via 2 shfl_xor across the 4 consecutive lanes of a row.
// ---------------------------------------------------------------------------
__global__ __launch_bounds__(256) void proj_mfma(
    const float* __restrict__ state, const unsigned short* __restrict__ WT,
    const float* __restrict__ bQ, const float* __restrict__ bK,
    const float* __restrict__ bV,
    unsigned short* __restrict__ Qb, unsigned char* __restrict__ KVb,
    float* __restrict__ scl)
{
    __shared__ float lbuf[4][16 * 132];

    const int tid  = threadIdx.x;
    const int wv   = tid >> 6;
    const int lane = tid & 63;
    const int lm   = lane & 15;    // A row / B col / C col within tile
    const int quad = lane >> 4;    // k-chunk select, C row group
    const int m0   = blockIdx.x * 64 + wv * 16;
    const int m    = m0 + lm;

    fp32x4 acc[3][8];
#pragma unroll
    for (int w = 0; w < 3; ++w)
#pragma unroll
        for (int t = 0; t < 8; ++t)
            acc[w][t] = (fp32x4){0.f, 0.f, 0.f, 0.f};

    const int kq = quad * 8;
#pragma unroll
    for (int kb = 0; kb < 128; kb += 32) {
        short8 a = (short8){0,0,0,0,0,0,0,0};
        if (m < NNODES) {
            const float4 f0 = *(const float4*)(state + (size_t)m * 128 + kb + kq);
            const float4 f1 = *(const float4*)(state + (size_t)m * 128 + kb + kq + 4);
            a[0] = (short)f2bf(f0.x); a[1] = (short)f2bf(f0.y);
            a[2] = (short)f2bf(f0.z); a[3] = (short)f2bf(f0.w);
            a[4] = (short)f2bf(f1.x); a[5] = (short)f2bf(f1.y);
            a[6] = (short)f2bf(f1.z); a[7] = (short)f2bf(f1.w);
        }
#pragma unroll
        for (int w = 0; w < 3; ++w) {
#pragma unroll
            for (int t = 0; t < 8; ++t) {
                const short8 b = *(const short8*)(WT + w * 16384 + (t * 16 + lm) * 128 + kb + kq);
                acc[w][t] = __builtin_amdgcn_mfma_f32_16x16x32_bf16(a, b, acc[w][t], 0, 0, 0);
            }
        }
    }

    const int rrow = lane >> 2;          // 0..15
    const int rcol = (lane & 3) * 32;    // 0,32,64,96
    const int grow = m0 + rrow;
#pragma unroll
    for (int w = 0; w < 3; ++w) {
        const float* bp = (w == 0) ? bQ : ((w == 1) ? bK : bV);
        float* L = &lbuf[wv][0];
#pragma unroll
        for (int t = 0; t < 8; ++t) {
            const float bb = bp[t * 16 + lm];
#pragma unroll
            for (int r = 0; r < 4; ++r)
                L[(quad * 4 + r) * 132 + t * 16 + lm] = acc[w][t][r] + bb;
        }
        __syncthreads();
        if (grow < NNODES) {
            float xv[32];
#pragma unroll
            for (int c = 0; c < 4; ++c) {
                const float* lp = &L[rrow * 132 + rcol + c * 8];   // 16B aligned
                const float4 x0 = *(const float4*)(lp);
                const float4 x1 = *(const float4*)(lp + 4);
                xv[c*8+0] = x0.x; xv[c*8+1] = x0.y; xv[c*8+2] = x0.z; xv[c*8+3] = x0.w;
                xv[c*8+4] = x1.x; xv[c*8+5] = x1.y; xv[c*8+6] = x1.z; xv[c*8+7] = x1.w;
            }
            if (w == 0) {
                unsigned short* gp = Qb + (size_t)grow * 128 + rcol;
#pragma unroll
                for (int c = 0; c < 4; ++c) {
                    short8 r;
#pragma unroll
                    for (int j = 0; j < 8; ++j) r[j] = (short)f2bf(xv[c*8+j]);
                    *(short8*)(gp + c * 8) = r;
                }
            } else {
                // int8 per-NODE symmetric quantization: row max via shfl
                // across the 4 consecutive lanes (same rrow, rcol 0/32/64/96)
                float mx = 0.f;
#pragma unroll
                for (int j = 0; j < 32; ++j) mx = fmaxf(mx, fabsf(xv[j]));
                mx = fmaxf(mx, __shfl_xor(mx, 1));
                mx = fmaxf(mx, __shfl_xor(mx, 2));
                const float inv = (mx > 0.f) ? 127.0f / mx : 0.f;
                unsigned int du[8];
#pragma unroll
                for (int d = 0; d < 8; ++d) {
                    const int b0 = (int)rintf(xv[d*4 + 0] * inv);
                    const int b1 = (int)rintf(xv[d*4 + 1] * inv);
                    const int b2 = (int)rintf(xv[d*4 + 2] * inv);
                    const int b3 = (int)rintf(xv[d*4 + 3] * inv);
                    du[d] = (unsigned)(b0 & 255) | ((unsigned)(b1 & 255) << 8)
                          | ((unsigned)(b2 & 255) << 16) | ((unsigned)(b3 & 255) << 24);
                }
                unsigned char* gp = KVb + (size_t)grow * 256 + ((w == 1) ? 0 : 128) + rcol;
                *(uint4*)(gp)      = (uint4){du[0], du[1], du[2], du[3]};
                *(uint4*)(gp + 16) = (uint4){du[4], du[5], du[6], du[7]};
                if ((lane & 3) == 0) {
                    if (w == 1) scl[(size_t)grow * 2 + 0] = mx * (1.0f / 508.0f);
                    else        scl[(size_t)grow * 2 + 1] = mx * (1.0f / 127.0f);
                }
            }
        }
        __syncthreads();
    }
}

// ---------------------------------------------------------------------------
// Counting-sort pass 1 (packed word (bucket<<24|src<<8|dstlow), wave shfl_up
// scan). Verified in round 5.
// ---------------------------------------------------------------------------
__global__ __launch_bounds__(256) void bucket_pass1(
    const int* __restrict__ src, const int* __restrict__ dst,
    int* __restrict__ gcur, int* __restrict__ pbuf)
{
    __shared__ int hist[256];
    __shared__ int lofs[256];
    __shared__ int gbase[256];
    __shared__ int wsum[4];
    __shared__ int pktg[2048];

    const int t = threadIdx.x;
    hist[t] = 0;
    __syncthreads();

    const long long e0 = (long long)blockIdx.x * 2048 + t * 8;
    const bool valid = (e0 < NEDGES);
    unsigned int w8[8]; int b8[8], r8[8];
    if (valid) {
        const int4 sA = *(const int4*)(src + e0);
        const int4 sB = *(const int4*)(src + e0 + 4);
        const int4 dA = *(const int4*)(dst + e0);
        const int4 dB = *(const int4*)(dst + e0 + 4);
        const int dd[8] = {dA.x, dA.y, dA.z, dA.w, dB.x, dB.y, dB.z, dB.w};
        const int ss[8] = {sA.x, sA.y, sA.z, sA.w, sB.x, sB.y, sB.z, sB.w};
#pragma unroll
        for (int j = 0; j < 8; ++j) {
            const int bb = dd[j] >> 8;
            b8[j] = bb;
            w8[j] = ((unsigned)bb << 24) | ((unsigned)ss[j] << 8) | (unsigned)(dd[j] & 255);
            r8[j] = atomicAdd(&hist[bb], 1);
        }
    }
    __syncthreads();

    const int v = hist[t];
    if (t < NB && v > 0) gbase[t] = atomicAdd(&gcur[t], v);

    int x = v;
#pragma unroll
    for (int off = 1; off < 64; off <<= 1) {
        const int y = __shfl_up(x, off);
        if ((t & 63) >= off) x += y;
    }
    if ((t & 63) == 63) wsum[t >> 6] = x;
    __syncthreads();
    int pre = 0;
#pragma unroll
    for (int ww = 0; ww < 4; ++ww)
        if (ww < (t >> 6)) pre += wsum[ww];
    const int tot = wsum[0] + wsum[1] + wsum[2] + wsum[3];
    lofs[t] = x + pre - v;          // exclusive prefix
    __syncthreads();

    if (valid) {
#pragma unroll
        for (int j = 0; j < 8; ++j)
            pktg[lofs[b8[j]] + r8[j]] = (int)w8[j];
    }
    __syncthreads();

#pragma unroll
    for (int j = 0; j < 8; ++j) {
        const int slot = t + 256 * j;
        if (slot < tot) {
            const unsigned int w = (unsigned int)pktg[slot];
            const int bb = (int)(w >> 24);
            const long long g = (long long)bb * BCAP + gbase[bb] + (slot - lofs[bb]);
            pbuf[g] = (int)(w & 0x00FFFFFFu);
        }
    }
}

// ---------------------------------------------------------------------------
// Counting-sort pass 2: one block per bucket, 1024 threads, packed word,
// wave shfl_up scan. Verified in round 5.
// ---------------------------------------------------------------------------
__global__ __launch_bounds__(1024) void bucket_pass2(
    const int* __restrict__ pbuf, const int* __restrict__ gcur,
    int* __restrict__ eidx, int2* __restrict__ offs2)
{
    __shared__ int hist[256];
    __shared__ int cur[256];
    __shared__ int wsum[4];
    __shared__ int pstash[BCAP];    // 40 KB packed words
    __shared__ int srcbuf[BCAP];    // 40 KB grouped src ids

    const int b = blockIdx.x;
    const int t = threadIdx.x;
    int cnt = gcur[b];
    if (cnt > BCAP) cnt = BCAP;
    const long long base = (long long)b * BCAP;

    if (t < 256) hist[t] = 0;
    __syncthreads();

    for (int i = t; i < cnt; i += 1024) {
        const int g = pbuf[base + i];
        pstash[i] = g;
        atomicAdd(&hist[g & 255], 1);
    }
    __syncthreads();

    int x = 0, v = 0;
    if (t < 256) {
        v = hist[t];
        x = v;
#pragma unroll
        for (int off = 1; off < 64; off <<= 1) {
            const int y = __shfl_up(x, off);
            if ((t & 63) >= off) x += y;
        }
        if ((t & 63) == 63) wsum[t >> 6] = x;
    }
    __syncthreads();
    if (t < 256) {
        int pre = 0;
#pragma unroll
        for (int ww = 0; ww < 4; ++ww)
            if (ww < (t >> 6)) pre += wsum[ww];
        const int ex = x + pre - v;          // exclusive
        cur[t] = ex;
        const int n = b * 256 + t;
        if (n < NNODES) {
            int2 oe; oe.x = (int)(base + ex); oe.y = (int)(base + ex + v);
            offs2[n] = oe;
        }
    }
    __syncthreads();

    for (int i = t; i < cnt; i += 1024) {
        const int g = pstash[i];
        const int p = atomicAdd(&cur[g & 255], 1);
        srcbuf[p] = g >> 8;
    }
    __syncthreads();

    for (int i = t; i < cnt; i += 1024)
        eidx[base + i] = srcbuf[i];
}

// ---------------------------------------------------------------------------
// Aggregation: one wave per dst node; lane = (edge-slot eo=l>>3, head h=l&7).
// Round-6 2-edge body (round-7's 4-edge unroll regressed: compiler kept
// VGPR=60 and serialized the gathers -> no added MLP, just VALU overhead).
// Round-8 change: scl is per-NODE float2 (400KB, L2-resident) loaded as a
// same-address broadcast across the 8 head lanes -- removes the third
// L3-bound request class per edge (the established limiter is per-CU miss
// slots x latency, warm rows at FETCH~0 prove cache-side latency-bound).
// ---------------------------------------------------------------------------
__global__ __launch_bounds__(256) void aggregate_kernel(
    const int* __restrict__ eidx, const int2* __restrict__ offs2,
    const unsigned short* __restrict__ Qb, const unsigned char* __restrict__ KVb,
    const float* __restrict__ scl, float* __restrict__ out)
{
    const int n = blockIdx.x * 4 + (threadIdx.x >> 6);
    const int l = threadIdx.x & 63;
    if (n >= NNODES) return;
    const int eo = l >> 3;       // edge slot 0..7
    const int h  = l & 7;        // head 0..7

    const unsigned short* qp = Qb + (size_t)n * 128 + h * 16;
    const uint4 qa = *(const uint4*)(qp);
    const uint4 qc = *(const uint4*)(qp + 8);
    float q[16];
    q[0]  = bflo(qa.x); q[1]  = bfhi(qa.x); q[2]  = bflo(qa.y); q[3]  = bfhi(qa.y);
    q[4]  = bflo(qa.z); q[5]  = bfhi(qa.z); q[6]  = bflo(qa.w); q[7]  = bfhi(qa.w);
    q[8]  = bflo(qc.x); q[9]  = bfhi(qc.x); q[10] = bflo(qc.y); q[11] = bfhi(qc.y);
    q[12] = bflo(qc.z); q[13] = bfhi(qc.z); q[14] = bflo(qc.w); q[15] = bfhi(qc.w);

    const int2 oe = offs2[n];
    const int beg = oe.x, end = oe.y;

    float acc[16];
#pragma unroll
    for (int j = 0; j < 16; ++j) acc[j] = 0.f;
    float zacc = 0.f;

    for (int i = beg; i < end; i += 16) {
        const int ei0 = i + eo;
        const int ei1 = ei0 + 8;
        const bool act0 = (ei0 < end);
        const bool act1 = (ei1 < end);
        const int s0 = eidx[act0 ? ei0 : beg];
        const int s1 = eidx[act1 ? ei1 : beg];

        const unsigned char* rp0 = KVb + (size_t)s0 * 256;
        const unsigned char* rp1 = KVb + (size_t)s1 * 256;
        const uint4 kw0 = *(const uint4*)(rp0 + h * 16);
        const uint4 vw0 = *(const uint4*)(rp0 + 128 + h * 16);
        const uint4 kw1 = *(const uint4*)(rp1 + h * 16);
        const uint4 vw1 = *(const uint4*)(rp1 + 128 + h * 16);
        const float2 sc0 = *(const float2*)(scl + (size_t)s0 * 2);
        const float2 sc1 = *(const float2*)(scl + (size_t)s1 * 2);

        float p0;
        p0 = sb2f(kw0.x, 0) * q[0];
        p0 = fmaf(sb2f(kw0.x, 1), q[1],  p0); p0 = fmaf(sb2f(kw0.x, 2), q[2],  p0);
        p0 = fmaf(sb2f(kw0.x, 3), q[3],  p0); p0 = fmaf(sb2f(kw0.y, 0), q[4],  p0);
        p0 = fmaf(sb2f(kw0.y, 1), q[5],  p0); p0 = fmaf(sb2f(kw0.y, 2), q[6],  p0);
        p0 = fmaf(sb2f(kw0.y, 3), q[7],  p0); p0 = fmaf(sb2f(kw0.z, 0), q[8],  p0);
        p0 = fmaf(sb2f(kw0.z, 1), q[9],  p0); p0 = fmaf(sb2f(kw0.z, 2), q[10], p0);
        p0 = fmaf(sb2f(kw0.z, 3), q[11], p0); p0 = fmaf(sb2f(kw0.w, 0), q[12], p0);
        p0 = fmaf(sb2f(kw0.w, 1), q[13], p0); p0 = fmaf(sb2f(kw0.w, 2), q[14], p0);
        p0 = fmaf(sb2f(kw0.w, 3), q[15], p0);
        p0 *= sc0.x;                      // kmax/(127*4): dequant + 1/sqrt(D)

        float p1;
        p1 = sb2f(kw1.x, 0) * q[0];
        p1 = fmaf(sb2f(kw1.x, 1), q[1],  p1); p1 = fmaf(sb2f(kw1.x, 2), q[2],  p1);
        p1 = fmaf(sb2f(kw1.x, 3), q[3],  p1); p1 = fmaf(sb2f(kw1.y, 0), q[4],  p1);
        p1 = fmaf(sb2f(kw1.y, 1), q[5],  p1); p1 = fmaf(sb2f(kw1.y, 2), q[6],  p1);
        p1 = fmaf(sb2f(kw1.y, 3), q[7],  p1); p1 = fmaf(sb2f(kw1.z, 0), q[8],  p1);
        p1 = fmaf(sb2f(kw1.z, 1), q[9],  p1); p1 = fmaf(sb2f(kw1.z, 2), q[10], p1);
        p1 = fmaf(sb2f(kw1.z, 3), q[11], p1); p1 = fmaf(sb2f(kw1.w, 0), q[12], p1);
        p1 = fmaf(sb2f(kw1.w, 1), q[13], p1); p1 = fmaf(sb2f(kw1.w, 2), q[14], p1);
        p1 = fmaf(sb2f(kw1.w, 3), q[15], p1);
        p1 *= sc1.x;

        float w0 = __expf(fminf(fmaxf(p0, -5.f), 5.f));
        float w1 = __expf(fminf(fmaxf(p1, -5.f), 5.f));
        w0 = act0 ? w0 : 0.f;
        w1 = act1 ? w1 : 0.f;
        zacc += w0 + w1;
        const float wv0 = w0 * sc0.y;     // fold vscale into the weight
        const float wv1 = w1 * sc1.y;

        acc[0]  = fmaf(sb2f(vw0.x, 0), wv0, acc[0]);  acc[1]  = fmaf(sb2f(vw0.x, 1), wv0, acc[1]);
        acc[2]  = fmaf(sb2f(vw0.x, 2), wv0, acc[2]);  acc[3]  = fmaf(sb2f(vw0.x, 3), wv0, acc[3]);
        acc[4]  = fmaf(sb2f(vw0.y, 0), wv0, acc[4]);  acc[5]  = fmaf(sb2f(vw0.y, 1), wv0, acc[5]);
        acc[6]  = fmaf(sb2f(vw0.y, 2), wv0, acc[6]);  acc[7]  = fmaf(sb2f(vw0.y, 3), wv0, acc[7]);
        acc[8]  = fmaf(sb2f(vw0.z, 0), wv0, acc[8]);  acc[9]  = fmaf(sb2f(vw0.z, 1), wv0, acc[9]);
        acc[10] = fmaf(sb2f(vw0.z, 2), wv0, acc[10]); acc[11] = fmaf(sb2f(vw0.z, 3), wv0, acc[11]);
        acc[12] = fmaf(sb2f(vw0.w, 0), wv0, acc[12]); acc[13] = fmaf(sb2f(vw0.w, 1), wv0, acc[13]);
        acc[14] = fmaf(sb2f(vw0.w, 2), wv0, acc[14]); acc[15] = fmaf(sb2f(vw0.w, 3), wv0, acc[15]);

        acc[0]  = fmaf(sb2f(vw1.x, 0), wv1, acc[0]);  acc[1]  = fmaf(sb2f(vw1.x, 1), wv1, acc[1]);
        acc[2]  = fmaf(sb2f(vw1.x, 2), wv1, acc[2]);  acc[3]  = fmaf(sb2f(vw1.x, 3), wv1, acc[3]);
        acc[4]  = fmaf(sb2f(vw1.y, 0), wv1, acc[4]);  acc[5]  = fmaf(sb2f(vw1.y, 1), wv1, acc[5]);
        acc[6]  = fmaf(sb2f(vw1.y, 2), wv1, acc[6]);  acc[7]  = fmaf(sb2f(vw1.y, 3), wv1, acc[7]);
        acc[8]  = fmaf(sb2f(vw1.z, 0), wv1, acc[8]);  acc[9]  = fmaf(sb2f(vw1.z, 1), wv1, acc[9]);
        acc[10] = fmaf(sb2f(vw1.z, 2), wv1, acc[10]); acc[11] = fmaf(sb2f(vw1.z, 3), wv1, acc[11]);
        acc[12] = fmaf(sb2f(vw1.w, 0), wv1, acc[12]); acc[13] = fmaf(sb2f(vw1.w, 1), wv1, acc[13]);
        acc[14] = fmaf(sb2f(vw1.w, 2), wv1, acc[14]); acc[15] = fmaf(sb2f(vw1.w, 3), wv1, acc[15]);
    }

    // reduce across edge slots (lanes differing in bits 3..5)
#pragma unroll
    for (int st = 8; st < 64; st <<= 1) {
        zacc += __shfl_xor(zacc, st);
#pragma unroll
        for (int j = 0; j < 16; ++j) acc[j] += __shfl_xor(acc[j], st);
    }

    if (eo == 0) {
        const float inv = 1.0f / zacc;
        float* op = out + (size_t)n * 128 + h * 16;
        *(float4*)(op)      = make_float4(acc[0]*inv,  acc[1]*inv,  acc[2]*inv,  acc[3]*inv);
        *(float4*)(op + 4)  = make_float4(acc[4]*inv,  acc[5]*inv,  acc[6]*inv,  acc[7]*inv);
        *(float4*)(op + 8)  = make_float4(acc[8]*inv,  acc[9]*inv,  acc[10]*inv, acc[11]*inv);
        *(float4*)(op + 12) = make_float4(acc[12]*inv, acc[13]*inv, acc[14]*inv, acc[15]*inv);
    }
}

extern "C" void kernel_launch(void* const* d_in, const int* in_sizes, int n_in,
                              void* d_out, int out_size, void* d_ws, size_t ws_size,
                              hipStream_t stream)
{
    const float* state = (const float*)d_in[0];
    const int*   src   = (const int*)d_in[1];
    const int*   dst   = (const int*)d_in[2];
    const float* WQ    = (const float*)d_in[3];
    const float* bQ    = (const float*)d_in[4];
    const float* WK    = (const float*)d_in[5];
    const float* bK    = (const float*)d_in[6];
    const float* WV    = (const float*)d_in[7];
    const float* bV    = (const float*)d_in[8];
    float* out = (float*)d_out;

    unsigned short* Qb  = (unsigned short*)d_ws;                        // 12.8 MB
    unsigned char*  KVb = (unsigned char*)(Qb + (size_t)NNODES * 128);  // 12.8 MB
    float*          scl = (float*)(KVb + (size_t)NNODES * 256);         // 400 KB
    unsigned short* WT  = (unsigned short*)(scl + (size_t)NNODES * 2);  // 96 KB
    int* pbuf  = (int*)(WT + 3 * 16384);                                // NB*BCAP*4B
    int* eidx  = pbuf + (size_t)NB * BCAP;
    int* gcur  = eidx + (size_t)NB * BCAP;                              // 256
    int2* offs2 = (int2*)(gcur + 256);                                  // 50000 int2

    cast_wt<<<3 * 128, 128, 0, stream>>>(WQ, WK, WV, WT, gcur);
    proj_mfma<<<(NNODES + 63) / 64, 256, 0, stream>>>(state, WT, bQ, bK, bV, Qb, KVb, scl);

    bucket_pass1<<<(NEDGES + 2047) / 2048, 256, 0, stream>>>(src, dst, gcur, pbuf);
    bucket_pass2<<<NB, 1024, 0, stream>>>(pbuf, gcur, eidx, offs2);

    aggregate_kernel<<<(NNODES + 3) / 4, 256, 0, stream>>>(eidx, offs2, Qb, KVb, scl, out);
}

// Round 9
// 235.706 us; speedup vs baseline: 1.0829x; 1.0276x over previous
//
#include <hip/hip_runtime.h>

#define NNODES 50000
#define NEDGES 1600000
#define NB 196        // buckets = dst>>8  (50000/256 -> 0..195)
#define BCAP 10240    // edges per bucket capacity (mean 8163, +20 sigma)

typedef __attribute__((ext_vector_type(8))) short short8;   // 8 x bf16
typedef __attribute__((ext_vector_type(4))) float fp32x4;   // MFMA C/D frag

#if defined(__has_builtin)
#if __has_builtin(__builtin_amdgcn_sdot4)
#define HAVE_SDOT4 1
#endif
#endif

__device__ __forceinline__ unsigned short f2bf(float f) {   // RNE fp32 -> bf16
    unsigned int u = __float_as_uint(f);
    u += 0x7fffu + ((u >> 16) & 1u);
    return (unsigned short)(u >> 16);
}

// signed-byte j of dword u -> float (v_bfe_i32 + v_cvt_f32_i32)
__device__ __forceinline__ float sb2f(unsigned int u, int j) {
    return (float)((int)(u << (24 - 8 * j)) >> 24);
}

// ---------------------------------------------------------------------------
// Cast + transpose W (128x128 fp32, k-major) -> WT bf16 (n-major).
// Also zeroes gcur (replaces a memset dispatch; runs before pass1 in-stream).
// ---------------------------------------------------------------------------
__global__ __launch_bounds__(128) void cast_wt(
    const float* __restrict__ WQ, const float* __restrict__ WK,
    const float* __restrict__ WV, unsigned short* __restrict__ WT,
    int* __restrict__ gcur)
{
    if (blockIdx.x == 0) {
        gcur[threadIdx.x] = 0;
        gcur[threadIdx.x + 128] = 0;
    }
    const int w = blockIdx.x >> 7;
    const int n = blockIdx.x & 127;
    const int k = threadIdx.x;
    const float* W = (w == 0) ? WQ : ((w == 1) ? WK : WV);
    WT[w * 16384 + n * 128 + k] = f2bf(W[k * 128 + n]);
}

// ---------------------------------------------------------------------------
// Fused QKV projection, bf16 MFMA 16x16x32. Round-9 outputs (ALL int8):
//   Qbi [n][128] int8  (6.4 MB -- was bf16 12.8; enables sdot4 K-dot)
//   KVb [n][256] int8: [K 128B | V 128B]  -- 2 cache lines/row
//   scl [n] float4 {kscale=kmax/508, vscale=vmax/127, qscale=qmax/127, 0}
// Per-NODE symmetric int8, row max via 2 shfl_xor over the 4 consecutive
// lanes of a row. p = idot * kscale * qscale is algebraically the same
// factorization as the round-8 float path (1/sqrt(16) folded in /508).
// ---------------------------------------------------------------------------
__global__ __launch_bounds__(256) void proj_mfma(
    const float* __restrict__ state, const unsigned short* __restrict__ WT,
    const float* __restrict__ bQ, const float* __restrict__ bK,
    const float* __restrict__ bV,
    unsigned char* __restrict__ Qbi, unsigned char* __restrict__ KVb,
    float* __restrict__ scl)
{
    __shared__ float lbuf[4][16 * 132];

    const int tid  = threadIdx.x;
    const int wv   = tid >> 6;
    const int lane = tid & 63;
    const int lm   = lane & 15;    // A row / B col / C col within tile
    const int quad = lane >> 4;    // k-chunk select, C row group
    const int m0   = blockIdx.x * 64 + wv * 16;
    const int m    = m0 + lm;

    fp32x4 acc[3][8];
#pragma unroll
    for (int w = 0; w < 3; ++w)
#pragma unroll
        for (int t = 0; t < 8; ++t)
            acc[w][t] = (fp32x4){0.f, 0.f, 0.f, 0.f};

    const int kq = quad * 8;
#pragma unroll
    for (int kb = 0; kb < 128; kb += 32) {
        short8 a = (short8){0,0,0,0,0,0,0,0};
        if (m < NNODES) {
            const float4 f0 = *(const float4*)(state + (size_t)m * 128 + kb + kq);
            const float4 f1 = *(const float4*)(state + (size_t)m * 128 + kb + kq + 4);
            a[0] = (short)f2bf(f0.x); a[1] = (short)f2bf(f0.y);
            a[2] = (short)f2bf(f0.z); a[3] = (short)f2bf(f0.w);
            a[4] = (short)f2bf(f1.x); a[5] = (short)f2bf(f1.y);
            a[6] = (short)f2bf(f1.z); a[7] = (short)f2bf(f1.w);
        }
#pragma unroll
        for (int w = 0; w < 3; ++w) {
#pragma unroll
            for (int t = 0; t < 8; ++t) {
                const short8 b = *(const short8*)(WT + w * 16384 + (t * 16 + lm) * 128 + kb + kq);
                acc[w][t] = __builtin_amdgcn_mfma_f32_16x16x32_bf16(a, b, acc[w][t], 0, 0, 0);
            }
        }
    }

    const int rrow = lane >> 2;          // 0..15
    const int rcol = (lane & 3) * 32;    // 0,32,64,96
    const int grow = m0 + rrow;
#pragma unroll
    for (int w = 0; w < 3; ++w) {
        const float* bp = (w == 0) ? bQ : ((w == 1) ? bK : bV);
        float* L = &lbuf[wv][0];
#pragma unroll
        for (int t = 0; t < 8; ++t) {
            const float bb = bp[t * 16 + lm];
#pragma unroll
            for (int r = 0; r < 4; ++r)
                L[(quad * 4 + r) * 132 + t * 16 + lm] = acc[w][t][r] + bb;
        }
        __syncthreads();
        if (grow < NNODES) {
            float xv[32];
#pragma unroll
            for (int c = 0; c < 4; ++c) {
                const float* lp = &L[rrow * 132 + rcol + c * 8];   // 16B aligned
                const float4 x0 = *(const float4*)(lp);
                const float4 x1 = *(const float4*)(lp + 4);
                xv[c*8+0] = x0.x; xv[c*8+1] = x0.y; xv[c*8+2] = x0.z; xv[c*8+3] = x0.w;
                xv[c*8+4] = x1.x; xv[c*8+5] = x1.y; xv[c*8+6] = x1.z; xv[c*8+7] = x1.w;
            }
            // int8 per-NODE symmetric quantization for Q, K, and V
            float mx = 0.f;
#pragma unroll
            for (int j = 0; j < 32; ++j) mx = fmaxf(mx, fabsf(xv[j]));
            mx = fmaxf(mx, __shfl_xor(mx, 1));
            mx = fmaxf(mx, __shfl_xor(mx, 2));
            const float inv = (mx > 0.f) ? 127.0f / mx : 0.f;
            unsigned int du[8];
#pragma unroll
            for (int d = 0; d < 8; ++d) {
                const int b0 = (int)rintf(xv[d*4 + 0] * inv);
                const int b1 = (int)rintf(xv[d*4 + 1] * inv);
                const int b2 = (int)rintf(xv[d*4 + 2] * inv);
                const int b3 = (int)rintf(xv[d*4 + 3] * inv);
                du[d] = (unsigned)(b0 & 255) | ((unsigned)(b1 & 255) << 8)
                      | ((unsigned)(b2 & 255) << 16) | ((unsigned)(b3 & 255) << 24);
            }
            unsigned char* gp;
            if (w == 0)      gp = Qbi + (size_t)grow * 128 + rcol;
            else if (w == 1) gp = KVb + (size_t)grow * 256 + rcol;
            else             gp = KVb + (size_t)grow * 256 + 128 + rcol;
            *(uint4*)(gp)      = (uint4){du[0], du[1], du[2], du[3]};
            *(uint4*)(gp + 16) = (uint4){du[4], du[5], du[6], du[7]};
            if ((lane & 3) == 0) {
                if (w == 0)      scl[(size_t)grow * 4 + 2] = mx * (1.0f / 127.0f);
                else if (w == 1) scl[(size_t)grow * 4 + 0] = mx * (1.0f / 508.0f);
                else             scl[(size_t)grow * 4 + 1] = mx * (1.0f / 127.0f);
            }
        }
        __syncthreads();
    }
}

// ---------------------------------------------------------------------------
// Counting-sort pass 1 (packed word (bucket<<24|src<<8|dstlow), wave shfl_up
// scan). Verified in round 5.
// ---------------------------------------------------------------------------
__global__ __launch_bounds__(256) void bucket_pass1(
    const int* __restrict__ src, const int* __restrict__ dst,
    int* __restrict__ gcur, int* __restrict__ pbuf)
{
    __shared__ int hist[256];
    __shared__ int lofs[256];
    __shared__ int gbase[256];
    __shared__ int wsum[4];
    __shared__ int pktg[2048];

    const int t = threadIdx.x;
    hist[t] = 0;
    __syncthreads();

    const long long e0 = (long long)blockIdx.x * 2048 + t * 8;
    const bool valid = (e0 < NEDGES);
    unsigned int w8[8]; int b8[8], r8[8];
    if (valid) {
        const int4 sA = *(const int4*)(src + e0);
        const int4 sB = *(const int4*)(src + e0 + 4);
        const int4 dA = *(const int4*)(dst + e0);
        const int4 dB = *(const int4*)(dst + e0 + 4);
        const int dd[8] = {dA.x, dA.y, dA.z, dA.w, dB.x, dB.y, dB.z, dB.w};
        const int ss[8] = {sA.x, sA.y, sA.z, sA.w, sB.x, sB.y, sB.z, sB.w};
#pragma unroll
        for (int j = 0; j < 8; ++j) {
            const int bb = dd[j] >> 8;
            b8[j] = bb;
            w8[j] = ((unsigned)bb << 24) | ((unsigned)ss[j] << 8) | (unsigned)(dd[j] & 255);
            r8[j] = atomicAdd(&hist[bb], 1);
        }
    }
    __syncthreads();

    const int v = hist[t];
    if (t < NB && v > 0) gbase[t] = atomicAdd(&gcur[t], v);

    int x = v;
#pragma unroll
    for (int off = 1; off < 64; off <<= 1) {
        const int y = __shfl_up(x, off);
        if ((t & 63) >= off) x += y;
    }
    if ((t & 63) == 63) wsum[t >> 6] = x;
    __syncthreads();
    int pre = 0;
#pragma unroll
    for (int ww = 0; ww < 4; ++ww)
        if (ww < (t >> 6)) pre += wsum[ww];
    const int tot = wsum[0] + wsum[1] + wsum[2] + wsum[3];
    lofs[t] = x + pre - v;          // exclusive prefix
    __syncthreads();

    if (valid) {
#pragma unroll
        for (int j = 0; j < 8; ++j)
            pktg[lofs[b8[j]] + r8[j]] = (int)w8[j];
    }
    __syncthreads();

#pragma unroll
    for (int j = 0; j < 8; ++j) {
        const int slot = t + 256 * j;
        if (slot < tot) {
            const unsigned int w = (unsigned int)pktg[slot];
            const int bb = (int)(w >> 24);
            const long long g = (long long)bb * BCAP + gbase[bb] + (slot - lofs[bb]);
            pbuf[g] = (int)(w & 0x00FFFFFFu);
        }
    }
}

// ---------------------------------------------------------------------------
// Counting-sort pass 2: one block per bucket, 1024 threads, packed word,
// wave shfl_up scan. Verified in round 5.
// ---------------------------------------------------------------------------
__global__ __launch_bounds__(1024) void bucket_pass2(
    const int* __restrict__ pbuf, const int* __restrict__ gcur,
    int* __restrict__ eidx, int2* __restrict__ offs2)
{
    __shared__ int hist[256];
    __shared__ int cur[256];
    __shared__ int wsum[4];
    __shared__ int pstash[BCAP];    // 40 KB packed words
    __shared__ int srcbuf[BCAP];    // 40 KB grouped src ids

    const int b = blockIdx.x;
    const int t = threadIdx.x;
    int cnt = gcur[b];
    if (cnt > BCAP) cnt = BCAP;
    const long long base = (long long)b * BCAP;

    if (t < 256) hist[t] = 0;
    __syncthreads();

    for (int i = t; i < cnt; i += 1024) {
        const int g = pbuf[base + i];
        pstash[i] = g;
        atomicAdd(&hist[g & 255], 1);
    }
    __syncthreads();

    int x = 0, v = 0;
    if (t < 256) {
        v = hist[t];
        x = v;
#pragma unroll
        for (int off = 1; off < 64; off <<= 1) {
            const int y = __shfl_up(x, off);
            if ((t & 63) >= off) x += y;
        }
        if ((t & 63) == 63) wsum[t >> 6] = x;
    }
    __syncthreads();
    if (t < 256) {
        int pre = 0;
#pragma unroll
        for (int ww = 0; ww < 4; ++ww)
            if (ww < (t >> 6)) pre += wsum[ww];
        const int ex = x + pre - v;          // exclusive
        cur[t] = ex;
        const int n = b * 256 + t;
        if (n < NNODES) {
            int2 oe; oe.x = (int)(base + ex); oe.y = (int)(base + ex + v);
            offs2[n] = oe;
        }
    }
    __syncthreads();

    for (int i = t; i < cnt; i += 1024) {
        const int g = pstash[i];
        const int p = atomicAdd(&cur[g & 255], 1);
        srcbuf[p] = g >> 8;
    }
    __syncthreads();

    for (int i = t; i < cnt; i += 1024)
        eidx[base + i] = srcbuf[i];
}

// ---------------------------------------------------------------------------
// Aggregation: one wave per dst node; lane = (edge-slot eo=l>>3, head h=l&7).
// Round-9: K-dot via v_dot4_i32_i8 (sdot4) on int8 Q x int8 K -- replaces
// 48 VALU ops (16 bfe + 16 cvt + 16 fma) with 4 sdot4 + 2 muls per edge-lane.
// Round-8 analysis: kernel is co-limited (VALU 57%, VALU floor ~41us of
// 71us); memory side is irreducible at 2 fully-consumed lines/edge. Scales:
// p = idot * (kmax/508) * (qmax/127) -- same factorization as the float
// path, only Q's quantization is new noise. Fallback decode path if the
// builtin is missing. V path unchanged (int8 decode + fma).
// ---------------------------------------------------------------------------
__global__ __launch_bounds__(256) void aggregate_kernel(
    const int* __restrict__ eidx, const int2* __restrict__ offs2,
    const unsigned char* __restrict__ Qbi, const unsigned char* __restrict__ KVb,
    const float* __restrict__ scl, float* __restrict__ out)
{
    const int n = blockIdx.x * 4 + (threadIdx.x >> 6);
    const int l = threadIdx.x & 63;
    if (n >= NNODES) return;
    const int eo = l >> 3;       // edge slot 0..7
    const int h  = l & 7;        // head 0..7

    const uint4 qw = *(const uint4*)(Qbi + (size_t)n * 128 + h * 16);
    const float qf = scl[(size_t)n * 4 + 2];       // qmax/127 (wave-uniform)
#ifndef HAVE_SDOT4
    float q[16];
    q[0]  = sb2f(qw.x, 0); q[1]  = sb2f(qw.x, 1); q[2]  = sb2f(qw.x, 2); q[3]  = sb2f(qw.x, 3);
    q[4]  = sb2f(qw.y, 0); q[5]  = sb2f(qw.y, 1); q[6]  = sb2f(qw.y, 2); q[7]  = sb2f(qw.y, 3);
    q[8]  = sb2f(qw.z, 0); q[9]  = sb2f(qw.z, 1); q[10] = sb2f(qw.z, 2); q[11] = sb2f(qw.z, 3);
    q[12] = sb2f(qw.w, 0); q[13] = sb2f(qw.w, 1); q[14] = sb2f(qw.w, 2); q[15] = sb2f(qw.w, 3);
#endif

    const int2 oe = offs2[n];
    const int beg = oe.x, end = oe.y;

    float acc[16];
#pragma unroll
    for (int j = 0; j < 16; ++j) acc[j] = 0.f;
    float zacc = 0.f;

    for (int i = beg; i < end; i += 16) {
        const int ei0 = i + eo;
        const int ei1 = ei0 + 8;
        const bool act0 = (ei0 < end);
        const bool act1 = (ei1 < end);
        const int s0 = eidx[act0 ? ei0 : beg];
        const int s1 = eidx[act1 ? ei1 : beg];

        const unsigned char* rp0 = KVb + (size_t)s0 * 256;
        const unsigned char* rp1 = KVb + (size_t)s1 * 256;
        const uint4 kw0 = *(const uint4*)(rp0 + h * 16);
        const uint4 vw0 = *(const uint4*)(rp0 + 128 + h * 16);
        const uint4 kw1 = *(const uint4*)(rp1 + h * 16);
        const uint4 vw1 = *(const uint4*)(rp1 + 128 + h * 16);
        const float2 sc0 = *(const float2*)(scl + (size_t)s0 * 4);
        const float2 sc1 = *(const float2*)(scl + (size_t)s1 * 4);

        float p0, p1;
#ifdef HAVE_SDOT4
        int id0 = __builtin_amdgcn_sdot4((int)kw0.x, (int)qw.x, 0,   false);
        id0     = __builtin_amdgcn_sdot4((int)kw0.y, (int)qw.y, id0, false);
        id0     = __builtin_amdgcn_sdot4((int)kw0.z, (int)qw.z, id0, false);
        id0     = __builtin_amdgcn_sdot4((int)kw0.w, (int)qw.w, id0, false);
        p0 = (float)id0 * (sc0.x * qf);
        int id1 = __builtin_amdgcn_sdot4((int)kw1.x, (int)qw.x, 0,   false);
        id1     = __builtin_amdgcn_sdot4((int)kw1.y, (int)qw.y, id1, false);
        id1     = __builtin_amdgcn_sdot4((int)kw1.z, (int)qw.z, id1, false);
        id1     = __builtin_amdgcn_sdot4((int)kw1.w, (int)qw.w, id1, false);
        p1 = (float)id1 * (sc1.x * qf);
#else
        p0 = sb2f(kw0.x, 0) * q[0];
        p0 = fmaf(sb2f(kw0.x, 1), q[1],  p0); p0 = fmaf(sb2f(kw0.x, 2), q[2],  p0);
        p0 = fmaf(sb2f(kw0.x, 3), q[3],  p0); p0 = fmaf(sb2f(kw0.y, 0), q[4],  p0);
        p0 = fmaf(sb2f(kw0.y, 1), q[5],  p0); p0 = fmaf(sb2f(kw0.y, 2), q[6],  p0);
        p0 = fmaf(sb2f(kw0.y, 3), q[7],  p0); p0 = fmaf(sb2f(kw0.z, 0), q[8],  p0);
        p0 = fmaf(sb2f(kw0.z, 1), q[9],  p0); p0 = fmaf(sb2f(kw0.z, 2), q[10], p0);
        p0 = fmaf(sb2f(kw0.z, 3), q[11], p0); p0 = fmaf(sb2f(kw0.w, 0), q[12], p0);
        p0 = fmaf(sb2f(kw0.w, 1), q[13], p0); p0 = fmaf(sb2f(kw0.w, 2), q[14], p0);
        p0 = fmaf(sb2f(kw0.w, 3), q[15], p0);
        p0 *= sc0.x * qf;
        p1 = sb2f(kw1.x, 0) * q[0];
        p1 = fmaf(sb2f(kw1.x, 1), q[1],  p1); p1 = fmaf(sb2f(kw1.x, 2), q[2],  p1);
        p1 = fmaf(sb2f(kw1.x, 3), q[3],  p1); p1 = fmaf(sb2f(kw1.y, 0), q[4],  p1);
        p1 = fmaf(sb2f(kw1.y, 1), q[5],  p1); p1 = fmaf(sb2f(kw1.y, 2), q[6],  p1);
        p1 = fmaf(sb2f(kw1.y, 3), q[7],  p1); p1 = fmaf(sb2f(kw1.z, 0), q[8],  p1);
        p1 = fmaf(sb2f(kw1.z, 1), q[9],  p1); p1 = fmaf(sb2f(kw1.z, 2), q[10], p1);
        p1 = fmaf(sb2f(kw1.z, 3), q[11], p1); p1 = fmaf(sb2f(kw1.w, 0), q[12], p1);
        p1 = fmaf(sb2f(kw1.w, 1), q[13], p1); p1 = fmaf(sb2f(kw1.w, 2), q[14], p1);
        p1 = fmaf(sb2f(kw1.w, 3), q[15], p1);
        p1 *= sc1.x * qf;
#endif

        float w0 = __expf(fminf(fmaxf(p0, -5.f), 5.f));
        float w1 = __expf(fminf(fmaxf(p1, -5.f), 5.f));
        w0 = act0 ? w0 : 0.f;
        w1 = act1 ? w1 : 0.f;
        zacc += w0 + w1;
        const float wv0 = w0 * sc0.y;     // fold vscale into the weight
        const float wv1 = w1 * sc1.y;

        acc[0]  = fmaf(sb2f(vw0.x, 0), wv0, acc[0]);  acc[1]  = fmaf(sb2f(vw0.x, 1), wv0, acc[1]);
        acc[2]  = fmaf(sb2f(vw0.x, 2), wv0, acc[2]);  acc[3]  = fmaf(sb2f(vw0.x, 3), wv0, acc[3]);
        acc[4]  = fmaf(sb2f(vw0.y, 0), wv0, acc[4]);  acc[5]  = fmaf(sb2f(vw0.y, 1), wv0, acc[5]);
        acc[6]  = fmaf(sb2f(vw0.y, 2), wv0, acc[6]);  acc[7]  = fmaf(sb2f(vw0.y, 3), wv0, acc[7]);
        acc[8]  = fmaf(sb2f(vw0.z, 0), wv0, acc[8]);  acc[9]  = fmaf(sb2f(vw0.z, 1), wv0, acc[9]);
        acc[10] = fmaf(sb2f(vw0.z, 2), wv0, acc[10]); acc[11] = fmaf(sb2f(vw0.z, 3), wv0, acc[11]);
        acc[12] = fmaf(sb2f(vw0.w, 0), wv0, acc[12]); acc[13] = fmaf(sb2f(vw0.w, 1), wv0, acc[13]);
        acc[14] = fmaf(sb2f(vw0.w, 2), wv0, acc[14]); acc[15] = fmaf(sb2f(vw0.w, 3), wv0, acc[15]);

        acc[0]  = fmaf(sb2f(vw1.x, 0), wv1, acc[0]);  acc[1]  = fmaf(sb2f(vw1.x, 1), wv1, acc[1]);
        acc[2]  = fmaf(sb2f(vw1.x, 2), wv1, acc[2]);  acc[3]  = fmaf(sb2f(vw1.x, 3), wv1, acc[3]);
        acc[4]  = fmaf(sb2f(vw1.y, 0), wv1, acc[4]);  acc[5]  = fmaf(sb2f(vw1.y, 1), wv1, acc[5]);
        acc[6]  = fmaf(sb2f(vw1.y, 2), wv1, acc[6]);  acc[7]  = fmaf(sb2f(vw1.y, 3), wv1, acc[7]);
        acc[8]  = fmaf(sb2f(vw1.z, 0), wv1, acc[8]);  acc[9]  = fmaf(sb2f(vw1.z, 1), wv1, acc[9]);
        acc[10] = fmaf(sb2f(vw1.z, 2), wv1, acc[10]); acc[11] = fmaf(sb2f(vw1.z, 3), wv1, acc[11]);
        acc[12] = fmaf(sb2f(vw1.w, 0), wv1, acc[12]); acc[13] = fmaf(sb2f(vw1.w, 1), wv1, acc[13]);
        acc[14] = fmaf(sb2f(vw1.w, 2), wv1, acc[14]); acc[15] = fmaf(sb2f(vw1.w, 3), wv1, acc[15]);
    }

    // reduce across edge slots (lanes differing in bits 3..5)
#pragma unroll
    for (int st = 8; st < 64; st <<= 1) {
        zacc += __shfl_xor(zacc, st);
#pragma unroll
        for (int j = 0; j < 16; ++j) acc[j] += __shfl_xor(acc[j], st);
    }

    if (eo == 0) {
        const float inv = 1.0f / zacc;
        float* op = out + (size_t)n * 128 + h * 16;
        *(float4*)(op)      = make_float4(acc[0]*inv,  acc[1]*inv,  acc[2]*inv,  acc[3]*inv);
        *(float4*)(op + 4)  = make_float4(acc[4]*inv,  acc[5]*inv,  acc[6]*inv,  acc[7]*inv);
        *(float4*)(op + 8)  = make_float4(acc[8]*inv,  acc[9]*inv,  acc[10]*inv, acc[11]*inv);
        *(float4*)(op + 12) = make_float4(acc[12]*inv, acc[13]*inv, acc[14]*inv, acc[15]*inv);
    }
}

extern "C" void kernel_launch(void* const* d_in, const int* in_sizes, int n_in,
                              void* d_out, int out_size, void* d_ws, size_t ws_size,
                              hipStream_t stream)
{
    const float* state = (const float*)d_in[0];
    const int*   src   = (const int*)d_in[1];
    const int*   dst   = (const int*)d_in[2];
    const float* WQ    = (const float*)d_in[3];
    const float* bQ    = (const float*)d_in[4];
    const float* WK    = (const float*)d_in[5];
    const float* bK    = (const float*)d_in[6];
    const float* WV    = (const float*)d_in[7];
    const float* bV    = (const float*)d_in[8];
    float* out = (float*)d_out;

    unsigned char*  Qbi = (unsigned char*)d_ws;                         // 6.4 MB
    unsigned char*  KVb = Qbi + (size_t)NNODES * 128;                   // 12.8 MB
    float*          scl = (float*)(KVb + (size_t)NNODES * 256);         // 800 KB
    unsigned short* WT  = (unsigned short*)(scl + (size_t)NNODES * 4);  // 96 KB
    int* pbuf  = (int*)(WT + 3 * 16384);                                // NB*BCAP*4B
    int* eidx  = pbuf + (size_t)NB * BCAP;
    int* gcur  = eidx + (size_t)NB * BCAP;                              // 256
    int2* offs2 = (int2*)(gcur + 256);                                  // 50000 int2

    cast_wt<<<3 * 128, 128, 0, stream>>>(WQ, WK, WV, WT, gcur);
    proj_mfma<<<(NNODES + 63) / 64, 256, 0, stream>>>(state, WT, bQ, bK, bV, Qbi, KVb, scl);

    bucket_pass1<<<(NEDGES + 2047) / 2048, 256, 0, stream>>>(src, dst, gcur, pbuf);
    bucket_pass2<<<NB, 1024, 0, stream>>>(pbuf, gcur, eidx, offs2);

    aggregate_kernel<<<(NNODES + 3) / 4, 256, 0, stream>>>(eidx, offs2, Qbi, KVb, scl, out);
}

// Round 10
// 213.746 us; speedup vs baseline: 1.1941x; 1.1027x over previous
//
#include <hip/hip_runtime.h>

#define NNODES 50000
#define NEDGES 1600000
#define NB 196        // buckets = dst>>8  (50000/256 -> 0..195)
#define BCAP 10240    // edges per bucket capacity (mean 8163, +20 sigma)

typedef __attribute__((ext_vector_type(8))) short short8;   // 8 x bf16
typedef __attribute__((ext_vector_type(4))) float fp32x4;   // MFMA C/D frag

#if defined(__has_builtin)
#if __has_builtin(__builtin_amdgcn_sdot4)
#define HAVE_SDOT4 1
#endif
#endif

__device__ __forceinline__ unsigned short f2bf(float f) {   // RNE fp32 -> bf16
    unsigned int u = __float_as_uint(f);
    u += 0x7fffu + ((u >> 16) & 1u);
    return (unsigned short)(u >> 16);
}

// signed-byte j of dword u -> float (v_bfe_i32 + v_cvt_f32_i32)
__device__ __forceinline__ float sb2f(unsigned int u, int j) {
    return (float)((int)(u << (24 - 8 * j)) >> 24);
}

// ---------------------------------------------------------------------------
// Cast + transpose W (128x128 fp32, k-major) -> WT bf16 (n-major).
// Also zeroes gcur (replaces a memset dispatch; runs before pass1 in-stream).
// ---------------------------------------------------------------------------
__global__ __launch_bounds__(128) void cast_wt(
    const float* __restrict__ WQ, const float* __restrict__ WK,
    const float* __restrict__ WV, unsigned short* __restrict__ WT,
    int* __restrict__ gcur)
{
    if (blockIdx.x == 0) {
        gcur[threadIdx.x] = 0;
        gcur[threadIdx.x + 128] = 0;
    }
    const int w = blockIdx.x >> 7;
    const int n = blockIdx.x & 127;
    const int k = threadIdx.x;
    const float* W = (w == 0) ? WQ : ((w == 1) ? WK : WV);
    WT[w * 16384 + n * 128 + k] = f2bf(W[k * 128 + n]);
}

// ---------------------------------------------------------------------------
// Fused QKV projection, bf16 MFMA 16x16x32, int8 outputs (round-9 codec).
// ROUND-10: B operands staged in LDS per kb instead of per-wave global
// gathers. Diagnosis: each wave privately gathered 96 short8 B-chunks/block
// -- 16 L2 lines per instr, 6144 line-requests/block, 4x redundant across
// the block's waves -> proj was L2-request-rate bound (~50us, hidden below
// the top-5 cutoff; round-4/5 subtraction gives proj+pass1 ~92us).
// Staging: per kb the block cooperatively loads 24KB (1536 chunks, slot
// s = tid+256j, LDS lane-linear, global addr decoded from s so the write is
// conflict-free and the read is ds_read_b128 at ((w*8+t)*64+lane)*16B).
// Chunk at slot s holds WT[w*16384+(t*16+lm)*128+kb+quad*8] for
// s=(w*8+t)*64+quad*16+lm; consumer lane=quad*16+lm reads slot
// (w*8+t)*64+lane -- identical bytes to the old per-wave load.
// LDS: 24KB B-stage unioned with the 33.8KB epilogue transpose buffer.
// ---------------------------------------------------------------------------
__global__ __launch_bounds__(256) void proj_mfma(
    const float* __restrict__ state, const unsigned short* __restrict__ WT,
    const float* __restrict__ bQ, const float* __restrict__ bK,
    const float* __restrict__ bV,
    unsigned char* __restrict__ Qbi, unsigned char* __restrict__ KVb,
    float* __restrict__ scl)
{
    __shared__ float smem[4 * 16 * 132];               // 33.8 KB (union)
    unsigned short* lwt = (unsigned short*)smem;       // first 24.6 KB: B tiles
    float* lbuf = smem;                                // epilogue transpose

    const int tid  = threadIdx.x;
    const int wv   = tid >> 6;
    const int lane = tid & 63;
    const int lm   = lane & 15;    // A row / B col / C col within tile
    const int quad = lane >> 4;    // k-chunk select, C row group
    const int m0   = blockIdx.x * 64 + wv * 16;
    const int m    = m0 + lm;

    fp32x4 acc[3][8];
#pragma unroll
    for (int w = 0; w < 3; ++w)
#pragma unroll
        for (int t = 0; t < 8; ++t)
            acc[w][t] = (fp32x4){0.f, 0.f, 0.f, 0.f};

    const int kq = quad * 8;
#pragma unroll
    for (int kb = 0; kb < 128; kb += 32) {
        // cooperative B stage: slot s is LDS-linear; global address decoded
        // from s (slm=s&15, squad=(s>>4)&3, stw=s>>6 -> w=stw>>3, t=stw&7)
        uint4 bstg[6];
#pragma unroll
        for (int j = 0; j < 6; ++j) {
            const int s = tid + 256 * j;
            const int slm = s & 15, squad = (s >> 4) & 3, stw = s >> 6;
            bstg[j] = *(const uint4*)(WT + (stw >> 3) * 16384
                                         + ((stw & 7) * 16 + slm) * 128
                                         + kb + squad * 8);
        }
        short8 a = (short8){0,0,0,0,0,0,0,0};
        if (m < NNODES) {
            const float4 f0 = *(const float4*)(state + (size_t)m * 128 + kb + kq);
            const float4 f1 = *(const float4*)(state + (size_t)m * 128 + kb + kq + 4);
            a[0] = (short)f2bf(f0.x); a[1] = (short)f2bf(f0.y);
            a[2] = (short)f2bf(f0.z); a[3] = (short)f2bf(f0.w);
            a[4] = (short)f2bf(f1.x); a[5] = (short)f2bf(f1.y);
            a[6] = (short)f2bf(f1.z); a[7] = (short)f2bf(f1.w);
        }
#pragma unroll
        for (int j = 0; j < 6; ++j)
            *(uint4*)((char*)lwt + (tid + 256 * j) * 16) = bstg[j];
        __syncthreads();
#pragma unroll
        for (int w = 0; w < 3; ++w) {
#pragma unroll
            for (int t = 0; t < 8; ++t) {
                const short8 b = *(const short8*)((char*)lwt + ((w * 8 + t) * 64 + lane) * 16);
                acc[w][t] = __builtin_amdgcn_mfma_f32_16x16x32_bf16(a, b, acc[w][t], 0, 0, 0);
            }
        }
        __syncthreads();
    }

    const int rrow = lane >> 2;          // 0..15
    const int rcol = (lane & 3) * 32;    // 0,32,64,96
    const int grow = m0 + rrow;
#pragma unroll
    for (int w = 0; w < 3; ++w) {
        const float* bp = (w == 0) ? bQ : ((w == 1) ? bK : bV);
        float* L = lbuf + wv * (16 * 132);
#pragma unroll
        for (int t = 0; t < 8; ++t) {
            const float bb = bp[t * 16 + lm];
#pragma unroll
            for (int r = 0; r < 4; ++r)
                L[(quad * 4 + r) * 132 + t * 16 + lm] = acc[w][t][r] + bb;
        }
        __syncthreads();
        if (grow < NNODES) {
            float xv[32];
#pragma unroll
            for (int c = 0; c < 4; ++c) {
                const float* lp = &L[rrow * 132 + rcol + c * 8];   // 16B aligned
                const float4 x0 = *(const float4*)(lp);
                const float4 x1 = *(const float4*)(lp + 4);
                xv[c*8+0] = x0.x; xv[c*8+1] = x0.y; xv[c*8+2] = x0.z; xv[c*8+3] = x0.w;
                xv[c*8+4] = x1.x; xv[c*8+5] = x1.y; xv[c*8+6] = x1.z; xv[c*8+7] = x1.w;
            }
            // int8 per-NODE symmetric quantization for Q, K, and V
            float mx = 0.f;
#pragma unroll
            for (int j = 0; j < 32; ++j) mx = fmaxf(mx, fabsf(xv[j]));
            mx = fmaxf(mx, __shfl_xor(mx, 1));
            mx = fmaxf(mx, __shfl_xor(mx, 2));
            const float inv = (mx > 0.f) ? 127.0f / mx : 0.f;
            unsigned int du[8];
#pragma unroll
            for (int d = 0; d < 8; ++d) {
                const int b0 = (int)rintf(xv[d*4 + 0] * inv);
                const int b1 = (int)rintf(xv[d*4 + 1] * inv);
                const int b2 = (int)rintf(xv[d*4 + 2] * inv);
                const int b3 = (int)rintf(xv[d*4 + 3] * inv);
                du[d] = (unsigned)(b0 & 255) | ((unsigned)(b1 & 255) << 8)
                      | ((unsigned)(b2 & 255) << 16) | ((unsigned)(b3 & 255) << 24);
            }
            unsigned char* gp;
            if (w == 0)      gp = Qbi + (size_t)grow * 128 + rcol;
            else if (w == 1) gp = KVb + (size_t)grow * 256 + rcol;
            else             gp = KVb + (size_t)grow * 256 + 128 + rcol;
            *(uint4*)(gp)      = (uint4){du[0], du[1], du[2], du[3]};
            *(uint4*)(gp + 16) = (uint4){du[4], du[5], du[6], du[7]};
            if ((lane & 3) == 0) {
                if (w == 0)      scl[(size_t)grow * 4 + 2] = mx * (1.0f / 127.0f);
                else if (w == 1) scl[(size_t)grow * 4 + 0] = mx * (1.0f / 508.0f);
                else             scl[(size_t)grow * 4 + 1] = mx * (1.0f / 127.0f);
            }
        }
        __syncthreads();
    }
}

// ---------------------------------------------------------------------------
// Counting-sort pass 1 (packed word (bucket<<24|src<<8|dstlow), wave shfl_up
// scan). Verified in round 5.
// ---------------------------------------------------------------------------
__global__ __launch_bounds__(256) void bucket_pass1(
    const int* __restrict__ src, const int* __restrict__ dst,
    int* __restrict__ gcur, int* __restrict__ pbuf)
{
    __shared__ int hist[256];
    __shared__ int lofs[256];
    __shared__ int gbase[256];
    __shared__ int wsum[4];
    __shared__ int pktg[2048];

    const int t = threadIdx.x;
    hist[t] = 0;
    __syncthreads();

    const long long e0 = (long long)blockIdx.x * 2048 + t * 8;
    const bool valid = (e0 < NEDGES);
    unsigned int w8[8]; int b8[8], r8[8];
    if (valid) {
        const int4 sA = *(const int4*)(src + e0);
        const int4 sB = *(const int4*)(src + e0 + 4);
        const int4 dA = *(const int4*)(dst + e0);
        const int4 dB = *(const int4*)(dst + e0 + 4);
        const int dd[8] = {dA.x, dA.y, dA.z, dA.w, dB.x, dB.y, dB.z, dB.w};
        const int ss[8] = {sA.x, sA.y, sA.z, sA.w, sB.x, sB.y, sB.z, sB.w};
#pragma unroll
        for (int j = 0; j < 8; ++j) {
            const int bb = dd[j] >> 8;
            b8[j] = bb;
            w8[j] = ((unsigned)bb << 24) | ((unsigned)ss[j] << 8) | (unsigned)(dd[j] & 255);
            r8[j] = atomicAdd(&hist[bb], 1);
        }
    }
    __syncthreads();

    const int v = hist[t];
    if (t < NB && v > 0) gbase[t] = atomicAdd(&gcur[t], v);

    int x = v;
#pragma unroll
    for (int off = 1; off < 64; off <<= 1) {
        const int y = __shfl_up(x, off);
        if ((t & 63) >= off) x += y;
    }
    if ((t & 63) == 63) wsum[t >> 6] = x;
    __syncthreads();
    int pre = 0;
#pragma unroll
    for (int ww = 0; ww < 4; ++ww)
        if (ww < (t >> 6)) pre += wsum[ww];
    const int tot = wsum[0] + wsum[1] + wsum[2] + wsum[3];
    lofs[t] = x + pre - v;          // exclusive prefix
    __syncthreads();

    if (valid) {
#pragma unroll
        for (int j = 0; j < 8; ++j)
            pktg[lofs[b8[j]] + r8[j]] = (int)w8[j];
    }
    __syncthreads();

#pragma unroll
    for (int j = 0; j < 8; ++j) {
        const int slot = t + 256 * j;
        if (slot < tot) {
            const unsigned int w = (unsigned int)pktg[slot];
            const int bb = (int)(w >> 24);
            const long long g = (long long)bb * BCAP + gbase[bb] + (slot - lofs[bb]);
            pbuf[g] = (int)(w & 0x00FFFFFFu);
        }
    }
}

// ---------------------------------------------------------------------------
// Counting-sort pass 2: one block per bucket, 1024 threads, packed word,
// wave shfl_up scan. ROUND-10: phase C scatters eidx directly
// (eidx[base+p] = g>>8, posted 4B writes into an L2-resident 32KB window)
// instead of LDS-grouping into srcbuf then copying -- drops a full
// 8-iteration pass, a barrier, and 40KB LDS.
// ---------------------------------------------------------------------------
__global__ __launch_bounds__(1024) void bucket_pass2(
    const int* __restrict__ pbuf, const int* __restrict__ gcur,
    int* __restrict__ eidx, int2* __restrict__ offs2)
{
    __shared__ int hist[256];
    __shared__ int cur[256];
    __shared__ int wsum[4];
    __shared__ int pstash[BCAP];    // 40 KB packed words

    const int b = blockIdx.x;
    const int t = threadIdx.x;
    int cnt = gcur[b];
    if (cnt > BCAP) cnt = BCAP;
    const long long base = (long long)b * BCAP;

    if (t < 256) hist[t] = 0;
    __syncthreads();

    for (int i = t; i < cnt; i += 1024) {
        const int g = pbuf[base + i];
        pstash[i] = g;
        atomicAdd(&hist[g & 255], 1);
    }
    __syncthreads();

    int x = 0, v = 0;
    if (t < 256) {
        v = hist[t];
        x = v;
#pragma unroll
        for (int off = 1; off < 64; off <<= 1) {
            const int y = __shfl_up(x, off);
            if ((t & 63) >= off) x += y;
        }
        if ((t & 63) == 63) wsum[t >> 6] = x;
    }
    __syncthreads();
    if (t < 256) {
        int pre = 0;
#pragma unroll
        for (int ww = 0; ww < 4; ++ww)
            if (ww < (t >> 6)) pre += wsum[ww];
        const int ex = x + pre - v;          // exclusive
        cur[t] = ex;
        const int n = b * 256 + t;
        if (n < NNODES) {
            int2 oe; oe.x = (int)(base + ex); oe.y = (int)(base + ex + v);
            offs2[n] = oe;
        }
    }
    __syncthreads();

    for (int i = t; i < cnt; i += 1024) {
        const int g = pstash[i];
        const int p = atomicAdd(&cur[g & 255], 1);
        eidx[base + p] = g >> 8;         // direct scatter (posted write)
    }
}

// ---------------------------------------------------------------------------
// Aggregation: one wave per dst node; lane = (edge-slot eo=l>>3, head h=l&7).
// Round-9 verified body (65us, absmax 0.043): sdot4 K-dot on int8 QxK,
// int8 V decode + fma, per-node scales, 2 cache lines/edge.
// ---------------------------------------------------------------------------
__global__ __launch_bounds__(256) void aggregate_kernel(
    const int* __restrict__ eidx, const int2* __restrict__ offs2,
    const unsigned char* __restrict__ Qbi, const unsigned char* __restrict__ KVb,
    const float* __restrict__ scl, float* __restrict__ out)
{
    const int n = blockIdx.x * 4 + (threadIdx.x >> 6);
    const int l = threadIdx.x & 63;
    if (n >= NNODES) return;
    const int eo = l >> 3;       // edge slot 0..7
    const int h  = l & 7;        // head 0..7

    const uint4 qw = *(const uint4*)(Qbi + (size_t)n * 128 + h * 16);
    const float qf = scl[(size_t)n * 4 + 2];       // qmax/127 (wave-uniform)
#ifndef HAVE_SDOT4
    float q[16];
    q[0]  = sb2f(qw.x, 0); q[1]  = sb2f(qw.x, 1); q[2]  = sb2f(qw.x, 2); q[3]  = sb2f(qw.x, 3);
    q[4]  = sb2f(qw.y, 0); q[5]  = sb2f(qw.y, 1); q[6]  = sb2f(qw.y, 2); q[7]  = sb2f(qw.y, 3);
    q[8]  = sb2f(qw.z, 0); q[9]  = sb2f(qw.z, 1); q[10] = sb2f(qw.z, 2); q[11] = sb2f(qw.z, 3);
    q[12] = sb2f(qw.w, 0); q[13] = sb2f(qw.w, 1); q[14] = sb2f(qw.w, 2); q[15] = sb2f(qw.w, 3);
#endif

    const int2 oe = offs2[n];
    const int beg = oe.x, end = oe.y;

    float acc[16];
#pragma unroll
    for (int j = 0; j < 16; ++j) acc[j] = 0.f;
    float zacc = 0.f;

    for (int i = beg; i < end; i += 16) {
        const int ei0 = i + eo;
        const int ei1 = ei0 + 8;
        const bool act0 = (ei0 < end);
        const bool act1 = (ei1 < end);
        const int s0 = eidx[act0 ? ei0 : beg];
        const int s1 = eidx[act1 ? ei1 : beg];

        const unsigned char* rp0 = KVb + (size_t)s0 * 256;
        const unsigned char* rp1 = KVb + (size_t)s1 * 256;
        const uint4 kw0 = *(const uint4*)(rp0 + h * 16);
        const uint4 vw0 = *(const uint4*)(rp0 + 128 + h * 16);
        const uint4 kw1 = *(const uint4*)(rp1 + h * 16);
        const uint4 vw1 = *(const uint4*)(rp1 + 128 + h * 16);
        const float2 sc0 = *(const float2*)(scl + (size_t)s0 * 4);
        const float2 sc1 = *(const float2*)(scl + (size_t)s1 * 4);

        float p0, p1;
#ifdef HAVE_SDOT4
        int id0 = __builtin_amdgcn_sdot4((int)kw0.x, (int)qw.x, 0,   false);
        id0     = __builtin_amdgcn_sdot4((int)kw0.y, (int)qw.y, id0, false);
        id0     = __builtin_amdgcn_sdot4((int)kw0.z, (int)qw.z, id0, false);
        id0     = __builtin_amdgcn_sdot4((int)kw0.w, (int)qw.w, id0, false);
        p0 = (float)id0 * (sc0.x * qf);
        int id1 = __builtin_amdgcn_sdot4((int)kw1.x, (int)qw.x, 0,   false);
        id1     = __builtin_amdgcn_sdot4((int)kw1.y, (int)qw.y, id1, false);
        id1     = __builtin_amdgcn_sdot4((int)kw1.z, (int)qw.z, id1, false);
        id1     = __builtin_amdgcn_sdot4((int)kw1.w, (int)qw.w, id1, false);
        p1 = (float)id1 * (sc1.x * qf);
#else
        p0 = sb2f(kw0.x, 0) * q[0];
        p0 = fmaf(sb2f(kw0.x, 1), q[1],  p0); p0 = fmaf(sb2f(kw0.x, 2), q[2],  p0);
        p0 = fmaf(sb2f(kw0.x, 3), q[3],  p0); p0 = fmaf(sb2f(kw0.y, 0), q[4],  p0);
        p0 = fmaf(sb2f(kw0.y, 1), q[5],  p0); p0 = fmaf(sb2f(kw0.y, 2), q[6],  p0);
        p0 = fmaf(sb2f(kw0.y, 3), q[7],  p0); p0 = fmaf(sb2f(kw0.z, 0), q[8],  p0);
        p0 = fmaf(sb2f(kw0.z, 1), q[9],  p0); p0 = fmaf(sb2f(kw0.z, 2), q[10], p0);
        p0 = fmaf(sb2f(kw0.z, 3), q[11], p0); p0 = fmaf(sb2f(kw0.w, 0), q[12], p0);
        p0 = fmaf(sb2f(kw0.w, 1), q[13], p0); p0 = fmaf(sb2f(kw0.w, 2), q[14], p0);
        p0 = fmaf(sb2f(kw0.w, 3), q[15], p0);
        p0 *= sc0.x * qf;
        p1 = sb2f(kw1.x, 0) * q[0];
        p1 = fmaf(sb2f(kw1.x, 1), q[1],  p1); p1 = fmaf(sb2f(kw1.x, 2), q[2],  p1);
        p1 = fmaf(sb2f(kw1.x, 3), q[3],  p1); p1 = fmaf(sb2f(kw1.y, 0), q[4],  p1);
        p1 = fmaf(sb2f(kw1.y, 1), q[5],  p1); p1 = fmaf(sb2f(kw1.y, 2), q[6],  p1);
        p1 = fmaf(sb2f(kw1.y, 3), q[7],  p1); p1 = fmaf(sb2f(kw1.z, 0), q[8],  p1);
        p1 = fmaf(sb2f(kw1.z, 1), q[9],  p1); p1 = fmaf(sb2f(kw1.z, 2), q[10], p1);
        p1 = fmaf(sb2f(kw1.z, 3), q[11], p1); p1 = fmaf(sb2f(kw1.w, 0), q[12], p1);
        p1 = fmaf(sb2f(kw1.w, 1), q[13], p1); p1 = fmaf(sb2f(kw1.w, 2), q[14], p1);
        p1 = fmaf(sb2f(kw1.w, 3), q[15], p1);
        p1 *= sc1.x * qf;
#endif

        float w0 = __expf(fminf(fmaxf(p0, -5.f), 5.f));
        float w1 = __expf(fminf(fmaxf(p1, -5.f), 5.f));
        w0 = act0 ? w0 : 0.f;
        w1 = act1 ? w1 : 0.f;
        zacc += w0 + w1;
        const float wv0 = w0 * sc0.y;     // fold vscale into the weight
        const float wv1 = w1 * sc1.y;

        acc[0]  = fmaf(sb2f(vw0.x, 0), wv0, acc[0]);  acc[1]  = fmaf(sb2f(vw0.x, 1), wv0, acc[1]);
        acc[2]  = fmaf(sb2f(vw0.x, 2), wv0, acc[2]);  acc[3]  = fmaf(sb2f(vw0.x, 3), wv0, acc[3]);
        acc[4]  = fmaf(sb2f(vw0.y, 0), wv0, acc[4]);  acc[5]  = fmaf(sb2f(vw0.y, 1), wv0, acc[5]);
        acc[6]  = fmaf(sb2f(vw0.y, 2), wv0, acc[6]);  acc[7]  = fmaf(sb2f(vw0.y, 3), wv0, acc[7]);
        acc[8]  = fmaf(sb2f(vw0.z, 0), wv0, acc[8]);  acc[9]  = fmaf(sb2f(vw0.z, 1), wv0, acc[9]);
        acc[10] = fmaf(sb2f(vw0.z, 2), wv0, acc[10]); acc[11] = fmaf(sb2f(vw0.z, 3), wv0, acc[11]);
        acc[12] = fmaf(sb2f(vw0.w, 0), wv0, acc[12]); acc[13] = fmaf(sb2f(vw0.w, 1), wv0, acc[13]);
        acc[14] = fmaf(sb2f(vw0.w, 2), wv0, acc[14]); acc[15] = fmaf(sb2f(vw0.w, 3), wv0, acc[15]);

        acc[0]  = fmaf(sb2f(vw1.x, 0), wv1, acc[0]);  acc[1]  = fmaf(sb2f(vw1.x, 1), wv1, acc[1]);
        acc[2]  = fmaf(sb2f(vw1.x, 2), wv1, acc[2]);  acc[3]  = fmaf(sb2f(vw1.x, 3), wv1, acc[3]);
        acc[4]  = fmaf(sb2f(vw1.y, 0), wv1, acc[4]);  acc[5]  = fmaf(sb2f(vw1.y, 1), wv1, acc[5]);
        acc[6]  = fmaf(sb2f(vw1.y, 2), wv1, acc[6]);  acc[7]  = fmaf(sb2f(vw1.y, 3), wv1, acc[7]);
        acc[8]  = fmaf(sb2f(vw1.z, 0), wv1, acc[8]);  acc[9]  = fmaf(sb2f(vw1.z, 1), wv1, acc[9]);
        acc[10] = fmaf(sb2f(vw1.z, 2), wv1, acc[10]); acc[11] = fmaf(sb2f(vw1.z, 3), wv1, acc[11]);
        acc[12] = fmaf(sb2f(vw1.w, 0), wv1, acc[12]); acc[13] = fmaf(sb2f(vw1.w, 1), wv1, acc[13]);
        acc[14] = fmaf(sb2f(vw1.w, 2), wv1, acc[14]); acc[15] = fmaf(sb2f(vw1.w, 3), wv1, acc[15]);
    }

    // reduce across edge slots (lanes differing in bits 3..5)
#pragma unroll
    for (int st = 8; st < 64; st <<= 1) {
        zacc += __shfl_xor(zacc, st);
#pragma unroll
        for (int j = 0; j < 16; ++j) acc[j] += __shfl_xor(acc[j], st);
    }

    if (eo == 0) {
        const float inv = 1.0f / zacc;
        float* op = out + (size_t)n * 128 + h * 16;
        *(float4*)(op)      = make_float4(acc[0]*inv,  acc[1]*inv,  acc[2]*inv,  acc[3]*inv);
        *(float4*)(op + 4)  = make_float4(acc[4]*inv,  acc[5]*inv,  acc[6]*inv,  acc[7]*inv);
        *(float4*)(op + 8)  = make_float4(acc[8]*inv,  acc[9]*inv,  acc[10]*inv, acc[11]*inv);
        *(float4*)(op + 12) = make_float4(acc[12]*inv, acc[13]*inv, acc[14]*inv, acc[15]*inv);
    }
}

extern "C" void kernel_launch(void* const* d_in, const int* in_sizes, int n_in,
                              void* d_out, int out_size, void* d_ws, size_t ws_size,
                              hipStream_t stream)
{
    const float* state = (const float*)d_in[0];
    const int*   src   = (const int*)d_in[1];
    const int*   dst   = (const int*)d_in[2];
    const float* WQ    = (const float*)d_in[3];
    const float* bQ    = (const float*)d_in[4];
    const float* WK    = (const float*)d_in[5];
    const float* bK    = (const float*)d_in[6];
    const float* WV    = (const float*)d_in[7];
    const float* bV    = (const float*)d_in[8];
    float* out = (float*)d_out;

    unsigned char*  Qbi = (unsigned char*)d_ws;                         // 6.4 MB
    unsigned char*  KVb = Qbi + (size_t)NNODES * 128;                   // 12.8 MB
    float*          scl = (float*)(KVb + (size_t)NNODES * 256);         // 800 KB
    unsigned short* WT  = (unsigned short*)(scl + (size_t)NNODES * 4);  // 96 KB
    int* pbuf  = (int*)(WT + 3 * 16384);                                // NB*BCAP*4B
    int* eidx  = pbuf + (size_t)NB * BCAP;
    int* gcur  = eidx + (size_t)NB * BCAP;                              // 256
    int2* offs2 = (int2*)(gcur + 256);                                  // 50000 int2

    cast_wt<<<3 * 128, 128, 0, stream>>>(WQ, WK, WV, WT, gcur);
    proj_mfma<<<(NNODES + 63) / 64, 256, 0, stream>>>(state, WT, bQ, bK, bV, Qbi, KVb, scl);

    bucket_pass1<<<(NEDGES + 2047) / 2048, 256, 0, stream>>>(src, dst, gcur, pbuf);
    bucket_pass2<<<NB, 1024, 0, stream>>>(pbuf, gcur, eidx, offs2);

    aggregate_kernel<<<(NNODES + 3) / 4, 256, 0, stream>>>(eidx, offs2, Qbi, KVb, scl, out);
}

// Round 11
// 210.662 us; speedup vs baseline: 1.2116x; 1.0146x over previous
//
#include <hip/hip_runtime.h>

#define NNODES 50000
#define NEDGES 1600000
#define NB 196        // buckets = dst>>8  (50000/256 -> 0..195)
#define BCAP 10240    // edges per bucket capacity (mean 8163, +20 sigma)
#define CWB 192       // cast_wt role blocks (2 n-cols each, 3*128 total)
#define P1B 782       // pass1 role blocks (2048 edges each)

typedef __attribute__((ext_vector_type(8))) short short8;   // 8 x bf16
typedef __attribute__((ext_vector_type(4))) float fp32x4;   // MFMA C/D frag

#if defined(__has_builtin)
#if __has_builtin(__builtin_amdgcn_sdot4)
#define HAVE_SDOT4 1
#endif
#endif

__device__ __forceinline__ unsigned short f2bf(float f) {   // RNE fp32 -> bf16
    unsigned int u = __float_as_uint(f);
    u += 0x7fffu + ((u >> 16) & 1u);
    return (unsigned short)(u >> 16);
}

// signed-byte j of dword u -> float (v_bfe_i32 + v_cvt_f32_i32)
__device__ __forceinline__ float sb2f(unsigned int u, int j) {
    return (float)((int)(u << (24 - 8 * j)) >> 24);
}

// ---------------------------------------------------------------------------
// MERGED: cast_wt + counting-sort pass 1. Round-11: the two have COMPATIBLE
// footprints (cast: no LDS, ~16 VGPR; pass1: 11.3KB LDS, ~48 VGPR) so unlike
// the round-4 proj+pass1 merge (33.8KB/108VGPR union -> occupancy collapse)
// this union costs nothing. cast_wt's ~5us hides entirely under pass1, and
// one dispatch boundary disappears. gcur zeroing moved to hipMemsetAsync.
//   blocks [0,CWB):   W transpose fp32->bf16 (2 n-cols per block, 256 thr)
//   blocks [CWB,..):  pass1 -- packed word (bucket<<24|src<<8|dstlow),
//                     wave shfl_up scan (round-5 verified body).
// ---------------------------------------------------------------------------
__global__ __launch_bounds__(256) void wt_p1(
    const float* __restrict__ WQ, const float* __restrict__ WK,
    const float* __restrict__ WV, unsigned short* __restrict__ WT,
    const int* __restrict__ src, const int* __restrict__ dst,
    int* __restrict__ gcur, int* __restrict__ pbuf)
{
    __shared__ int hist[256];
    __shared__ int lofs[256];
    __shared__ int gbase[256];
    __shared__ int wsum[4];
    __shared__ int pktg[2048];

    const int t = threadIdx.x;

    if (blockIdx.x < CWB) {
        const int task = blockIdx.x * 2 + (t >> 7);   // 0..383
        const int w = task >> 7;                      // 0..2
        const int n = task & 127;
        const int k = t & 127;
        const float* W = (w == 0) ? WQ : ((w == 1) ? WK : WV);
        WT[w * 16384 + n * 128 + k] = f2bf(W[k * 128 + n]);
        return;
    }
    const int bid = blockIdx.x - CWB;

    hist[t] = 0;
    __syncthreads();

    const long long e0 = (long long)bid * 2048 + t * 8;
    const bool valid = (e0 < NEDGES);
    unsigned int w8[8]; int b8[8], r8[8];
    if (valid) {
        const int4 sA = *(const int4*)(src + e0);
        const int4 sB = *(const int4*)(src + e0 + 4);
        const int4 dA = *(const int4*)(dst + e0);
        const int4 dB = *(const int4*)(dst + e0 + 4);
        const int dd[8] = {dA.x, dA.y, dA.z, dA.w, dB.x, dB.y, dB.z, dB.w};
        const int ss[8] = {sA.x, sA.y, sA.z, sA.w, sB.x, sB.y, sB.z, sB.w};
#pragma unroll
        for (int j = 0; j < 8; ++j) {
            const int bb = dd[j] >> 8;
            b8[j] = bb;
            w8[j] = ((unsigned)bb << 24) | ((unsigned)ss[j] << 8) | (unsigned)(dd[j] & 255);
            r8[j] = atomicAdd(&hist[bb], 1);
        }
    }
    __syncthreads();

    const int v = hist[t];
    if (t < NB && v > 0) gbase[t] = atomicAdd(&gcur[t], v);

    int x = v;
#pragma unroll
    for (int off = 1; off < 64; off <<= 1) {
        const int y = __shfl_up(x, off);
        if ((t & 63) >= off) x += y;
    }
    if ((t & 63) == 63) wsum[t >> 6] = x;
    __syncthreads();
    int pre = 0;
#pragma unroll
    for (int ww = 0; ww < 4; ++ww)
        if (ww < (t >> 6)) pre += wsum[ww];
    const int tot = wsum[0] + wsum[1] + wsum[2] + wsum[3];
    lofs[t] = x + pre - v;          // exclusive prefix
    __syncthreads();

    if (valid) {
#pragma unroll
        for (int j = 0; j < 8; ++j)
            pktg[lofs[b8[j]] + r8[j]] = (int)w8[j];
    }
    __syncthreads();

#pragma unroll
    for (int j = 0; j < 8; ++j) {
        const int slot = t + 256 * j;
        if (slot < tot) {
            const unsigned int w = (unsigned int)pktg[slot];
            const int bb = (int)(w >> 24);
            const long long g = (long long)bb * BCAP + gbase[bb] + (slot - lofs[bb]);
            pbuf[g] = (int)(w & 0x00FFFFFFu);
        }
    }
}

// ---------------------------------------------------------------------------
// Fused QKV projection, bf16 MFMA 16x16x32, int8 outputs (round-9 codec),
// per-kb cooperative LDS staging of B (round-10 verified: removed the 4x
// redundant per-wave L2 gathers, -16us).
// ---------------------------------------------------------------------------
__global__ __launch_bounds__(256) void proj_mfma(
    const float* __restrict__ state, const unsigned short* __restrict__ WT,
    const float* __restrict__ bQ, const float* __restrict__ bK,
    const float* __restrict__ bV,
    unsigned char* __restrict__ Qbi, unsigned char* __restrict__ KVb,
    float* __restrict__ scl)
{
    __shared__ float smem[4 * 16 * 132];               // 33.8 KB (union)
    unsigned short* lwt = (unsigned short*)smem;       // first 24.6 KB: B tiles
    float* lbuf = smem;                                // epilogue transpose

    const int tid  = threadIdx.x;
    const int wv   = tid >> 6;
    const int lane = tid & 63;
    const int lm   = lane & 15;    // A row / B col / C col within tile
    const int quad = lane >> 4;    // k-chunk select, C row group
    const int m0   = blockIdx.x * 64 + wv * 16;
    const int m    = m0 + lm;

    fp32x4 acc[3][8];
#pragma unroll
    for (int w = 0; w < 3; ++w)
#pragma unroll
        for (int t = 0; t < 8; ++t)
            acc[w][t] = (fp32x4){0.f, 0.f, 0.f, 0.f};

    const int kq = quad * 8;
#pragma unroll
    for (int kb = 0; kb < 128; kb += 32) {
        // cooperative B stage: slot s is LDS-linear; global address decoded
        // from s (slm=s&15, squad=(s>>4)&3, stw=s>>6 -> w=stw>>3, t=stw&7)
        uint4 bstg[6];
#pragma unroll
        for (int j = 0; j < 6; ++j) {
            const int s = tid + 256 * j;
            const int slm = s & 15, squad = (s >> 4) & 3, stw = s >> 6;
            bstg[j] = *(const uint4*)(WT + (stw >> 3) * 16384
                                         + ((stw & 7) * 16 + slm) * 128
                                         + kb + squad * 8);
        }
        short8 a = (short8){0,0,0,0,0,0,0,0};
        if (m < NNODES) {
            const float4 f0 = *(const float4*)(state + (size_t)m * 128 + kb + kq);
            const float4 f1 = *(const float4*)(state + (size_t)m * 128 + kb + kq + 4);
            a[0] = (short)f2bf(f0.x); a[1] = (short)f2bf(f0.y);
            a[2] = (short)f2bf(f0.z); a[3] = (short)f2bf(f0.w);
            a[4] = (short)f2bf(f1.x); a[5] = (short)f2bf(f1.y);
            a[6] = (short)f2bf(f1.z); a[7] = (short)f2bf(f1.w);
        }
#pragma unroll
        for (int j = 0; j < 6; ++j)
            *(uint4*)((char*)lwt + (tid + 256 * j) * 16) = bstg[j];
        __syncthreads();
#pragma unroll
        for (int w = 0; w < 3; ++w) {
#pragma unroll
            for (int t = 0; t < 8; ++t) {
                const short8 b = *(const short8*)((char*)lwt + ((w * 8 + t) * 64 + lane) * 16);
                acc[w][t] = __builtin_amdgcn_mfma_f32_16x16x32_bf16(a, b, acc[w][t], 0, 0, 0);
            }
        }
        __syncthreads();
    }

    const int rrow = lane >> 2;          // 0..15
    const int rcol = (lane & 3) * 32;    // 0,32,64,96
    const int grow = m0 + rrow;
#pragma unroll
    for (int w = 0; w < 3; ++w) {
        const float* bp = (w == 0) ? bQ : ((w == 1) ? bK : bV);
        float* L = lbuf + wv * (16 * 132);
#pragma unroll
        for (int t = 0; t < 8; ++t) {
            const float bb = bp[t * 16 + lm];
#pragma unroll
            for (int r = 0; r < 4; ++r)
                L[(quad * 4 + r) * 132 + t * 16 + lm] = acc[w][t][r] + bb;
        }
        __syncthreads();
        if (grow < NNODES) {
            float xv[32];
#pragma unroll
            for (int c = 0; c < 4; ++c) {
                const float* lp = &L[rrow * 132 + rcol + c * 8];   // 16B aligned
                const float4 x0 = *(const float4*)(lp);
                const float4 x1 = *(const float4*)(lp + 4);
                xv[c*8+0] = x0.x; xv[c*8+1] = x0.y; xv[c*8+2] = x0.z; xv[c*8+3] = x0.w;
                xv[c*8+4] = x1.x; xv[c*8+5] = x1.y; xv[c*8+6] = x1.z; xv[c*8+7] = x1.w;
            }
            // int8 per-NODE symmetric quantization for Q, K, and V
            float mx = 0.f;
#pragma unroll
            for (int j = 0; j < 32; ++j) mx = fmaxf(mx, fabsf(xv[j]));
            mx = fmaxf(mx, __shfl_xor(mx, 1));
            mx = fmaxf(mx, __shfl_xor(mx, 2));
            const float inv = (mx > 0.f) ? 127.0f / mx : 0.f;
            unsigned int du[8];
#pragma unroll
            for (int d = 0; d < 8; ++d) {
                const int b0 = (int)rintf(xv[d*4 + 0] * inv);
                const int b1 = (int)rintf(xv[d*4 + 1] * inv);
                const int b2 = (int)rintf(xv[d*4 + 2] * inv);
                const int b3 = (int)rintf(xv[d*4 + 3] * inv);
                du[d] = (unsigned)(b0 & 255) | ((unsigned)(b1 & 255) << 8)
                      | ((unsigned)(b2 & 255) << 16) | ((unsigned)(b3 & 255) << 24);
            }
            unsigned char* gp;
            if (w == 0)      gp = Qbi + (size_t)grow * 128 + rcol;
            else if (w == 1) gp = KVb + (size_t)grow * 256 + rcol;
            else             gp = KVb + (size_t)grow * 256 + 128 + rcol;
            *(uint4*)(gp)      = (uint4){du[0], du[1], du[2], du[3]};
            *(uint4*)(gp + 16) = (uint4){du[4], du[5], du[6], du[7]};
            if ((lane & 3) == 0) {
                if (w == 0)      scl[(size_t)grow * 4 + 2] = mx * (1.0f / 127.0f);
                else if (w == 1) scl[(size_t)grow * 4 + 0] = mx * (1.0f / 508.0f);
                else             scl[(size_t)grow * 4 + 1] = mx * (1.0f / 127.0f);
            }
        }
        __syncthreads();
    }
}

// ---------------------------------------------------------------------------
// Counting-sort pass 2: one block per bucket, 1024 threads, packed word,
// wave shfl_up scan, direct eidx scatter (round-10 verified).
// ---------------------------------------------------------------------------
__global__ __launch_bounds__(1024) void bucket_pass2(
    const int* __restrict__ pbuf, const int* __restrict__ gcur,
    int* __restrict__ eidx, int2* __restrict__ offs2)
{
    __shared__ int hist[256];
    __shared__ int cur[256];
    __shared__ int wsum[4];
    __shared__ int pstash[BCAP];    // 40 KB packed words

    const int b = blockIdx.x;
    const int t = threadIdx.x;
    int cnt = gcur[b];
    if (cnt > BCAP) cnt = BCAP;
    const long long base = (long long)b * BCAP;

    if (t < 256) hist[t] = 0;
    __syncthreads();

    for (int i = t; i < cnt; i += 1024) {
        const int g = pbuf[base + i];
        pstash[i] = g;
        atomicAdd(&hist[g & 255], 1);
    }
    __syncthreads();

    int x = 0, v = 0;
    if (t < 256) {
        v = hist[t];
        x = v;
#pragma unroll
        for (int off = 1; off < 64; off <<= 1) {
            const int y = __shfl_up(x, off);
            if ((t & 63) >= off) x += y;
        }
        if ((t & 63) == 63) wsum[t >> 6] = x;
    }
    __syncthreads();
    if (t < 256) {
        int pre = 0;
#pragma unroll
        for (int ww = 0; ww < 4; ++ww)
            if (ww < (t >> 6)) pre += wsum[ww];
        const int ex = x + pre - v;          // exclusive
        cur[t] = ex;
        const int n = b * 256 + t;
        if (n < NNODES) {
            int2 oe; oe.x = (int)(base + ex); oe.y = (int)(base + ex + v);
            offs2[n] = oe;
        }
    }
    __syncthreads();

    for (int i = t; i < cnt; i += 1024) {
        const int g = pstash[i];
        const int p = atomicAdd(&cur[g & 255], 1);
        eidx[base + p] = g >> 8;         // direct scatter (posted write)
    }
}

// ---------------------------------------------------------------------------
// Aggregation: one wave per dst node; lane = (edge-slot eo=l>>3, head h=l&7).
// Round-9 sdot4 body + ROUND-11 eidx pipeline: prefetch next iteration's
// indices before this iteration's compute. Round-1's identical prefetch was
// neutral -- but that was the 512B-row saturation regime (miss queue full,
// latency-hiding irrelevant). Now (256B rows, VALU 44%, occ 44%, neither
// pipe saturated) the serial chain eidx(~200cy) -> KV(~500cy) -> compute is
// the limiter and 3.5 waves/SIMD fall just short of covering it; breaking
// the eidx hop off the chain is the marginal fix (regime-gated retry).
// ---------------------------------------------------------------------------
__global__ __launch_bounds__(256) void aggregate_kernel(
    const int* __restrict__ eidx, const int2* __restrict__ offs2,
    const unsigned char* __restrict__ Qbi, const unsigned char* __restrict__ KVb,
    const float* __restrict__ scl, float* __restrict__ out)
{
    const int n = blockIdx.x * 4 + (threadIdx.x >> 6);
    const int l = threadIdx.x & 63;
    if (n >= NNODES) return;
    const int eo = l >> 3;       // edge slot 0..7
    const int h  = l & 7;        // head 0..7

    const int2 oe = offs2[n];
    const int beg = oe.x, end = oe.y;

    // issue first iteration's index gathers before anything else
    const int pi0 = beg + eo;
    const int pi1 = pi0 + 8;
    int s0 = eidx[(pi0 < end) ? pi0 : beg];
    int s1 = eidx[(pi1 < end) ? pi1 : beg];

    const uint4 qw = *(const uint4*)(Qbi + (size_t)n * 128 + h * 16);
    const float qf = scl[(size_t)n * 4 + 2];       // qmax/127 (wave-uniform)
#ifndef HAVE_SDOT4
    float q[16];
    q[0]  = sb2f(qw.x, 0); q[1]  = sb2f(qw.x, 1); q[2]  = sb2f(qw.x, 2); q[3]  = sb2f(qw.x, 3);
    q[4]  = sb2f(qw.y, 0); q[5]  = sb2f(qw.y, 1); q[6]  = sb2f(qw.y, 2); q[7]  = sb2f(qw.y, 3);
    q[8]  = sb2f(qw.z, 0); q[9]  = sb2f(qw.z, 1); q[10] = sb2f(qw.z, 2); q[11] = sb2f(qw.z, 3);
    q[12] = sb2f(qw.w, 0); q[13] = sb2f(qw.w, 1); q[14] = sb2f(qw.w, 2); q[15] = sb2f(qw.w, 3);
#endif

    float acc[16];
#pragma unroll
    for (int j = 0; j < 16; ++j) acc[j] = 0.f;
    float zacc = 0.f;

    for (int i = beg; i < end; i += 16) {
        const bool act0 = (i + eo < end);
        const bool act1 = (i + eo + 8 < end);
        const int cs0 = s0;
        const int cs1 = s1;

        // next iteration's index gathers complete under this iteration's
        // KV loads + compute
        const int ni0 = i + 16 + eo;
        const int ni1 = ni0 + 8;
        s0 = eidx[(ni0 < end) ? ni0 : beg];
        s1 = eidx[(ni1 < end) ? ni1 : beg];

        const unsigned char* rp0 = KVb + (size_t)cs0 * 256;
        const unsigned char* rp1 = KVb + (size_t)cs1 * 256;
        const uint4 kw0 = *(const uint4*)(rp0 + h * 16);
        const uint4 vw0 = *(const uint4*)(rp0 + 128 + h * 16);
        const uint4 kw1 = *(const uint4*)(rp1 + h * 16);
        const uint4 vw1 = *(const uint4*)(rp1 + 128 + h * 16);
        const float2 sc0 = *(const float2*)(scl + (size_t)cs0 * 4);
        const float2 sc1 = *(const float2*)(scl + (size_t)cs1 * 4);

        float p0, p1;
#ifdef HAVE_SDOT4
        int id0 = __builtin_amdgcn_sdot4((int)kw0.x, (int)qw.x, 0,   false);
        id0     = __builtin_amdgcn_sdot4((int)kw0.y, (int)qw.y, id0, false);
        id0     = __builtin_amdgcn_sdot4((int)kw0.z, (int)qw.z, id0, false);
        id0     = __builtin_amdgcn_sdot4((int)kw0.w, (int)qw.w, id0, false);
        p0 = (float)id0 * (sc0.x * qf);
        int id1 = __builtin_amdgcn_sdot4((int)kw1.x, (int)qw.x, 0,   false);
        id1     = __builtin_amdgcn_sdot4((int)kw1.y, (int)qw.y, id1, false);
        id1     = __builtin_amdgcn_sdot4((int)kw1.z, (int)qw.z, id1, false);
        id1     = __builtin_amdgcn_sdot4((int)kw1.w, (int)qw.w, id1, false);
        p1 = (float)id1 * (sc1.x * qf);
#else
        p0 = sb2f(kw0.x, 0) * q[0];
        p0 = fmaf(sb2f(kw0.x, 1), q[1],  p0); p0 = fmaf(sb2f(kw0.x, 2), q[2],  p0);
        p0 = fmaf(sb2f(kw0.x, 3), q[3],  p0); p0 = fmaf(sb2f(kw0.y, 0), q[4],  p0);
        p0 = fmaf(sb2f(kw0.y, 1), q[5],  p0); p0 = fmaf(sb2f(kw0.y, 2), q[6],  p0);
        p0 = fmaf(sb2f(kw0.y, 3), q[7],  p0); p0 = fmaf(sb2f(kw0.z, 0), q[8],  p0);
        p0 = fmaf(sb2f(kw0.z, 1), q[9],  p0); p0 = fmaf(sb2f(kw0.z, 2), q[10], p0);
        p0 = fmaf(sb2f(kw0.z, 3), q[11], p0); p0 = fmaf(sb2f(kw0.w, 0), q[12], p0);
        p0 = fmaf(sb2f(kw0.w, 1), q[13], p0); p0 = fmaf(sb2f(kw0.w, 2), q[14], p0);
        p0 = fmaf(sb2f(kw0.w, 3), q[15], p0);
        p0 *= sc0.x * qf;
        p1 = sb2f(kw1.x, 0) * q[0];
        p1 = fmaf(sb2f(kw1.x, 1), q[1],  p1); p1 = fmaf(sb2f(kw1.x, 2), q[2],  p1);
        p1 = fmaf(sb2f(kw1.x, 3), q[3],  p1); p1 = fmaf(sb2f(kw1.y, 0), q[4],  p1);
        p1 = fmaf(sb2f(kw1.y, 1), q[5],  p1); p1 = fmaf(sb2f(kw1.y, 2), q[6],  p1);
        p1 = fmaf(sb2f(kw1.y, 3), q[7],  p1); p1 = fmaf(sb2f(kw1.z, 0), q[8],  p1);
        p1 = fmaf(sb2f(kw1.z, 1), q[9],  p1); p1 = fmaf(sb2f(kw1.z, 2), q[10], p1);
        p1 = fmaf(sb2f(kw1.z, 3), q[11], p1); p1 = fmaf(sb2f(kw1.w, 0), q[12], p1);
        p1 = fmaf(sb2f(kw1.w, 1), q[13], p1); p1 = fmaf(sb2f(kw1.w, 2), q[14], p1);
        p1 = fmaf(sb2f(kw1.w, 3), q[15], p1);
        p1 *= sc1.x * qf;
#endif

        float w0 = __expf(fminf(fmaxf(p0, -5.f), 5.f));
        float w1 = __expf(fminf(fmaxf(p1, -5.f), 5.f));
        w0 = act0 ? w0 : 0.f;
        w1 = act1 ? w1 : 0.f;
        zacc += w0 + w1;
        const float wv0 = w0 * sc0.y;     // fold vscale into the weight
        const float wv1 = w1 * sc1.y;

        acc[0]  = fmaf(sb2f(vw0.x, 0), wv0, acc[0]);  acc[1]  = fmaf(sb2f(vw0.x, 1), wv0, acc[1]);
        acc[2]  = fmaf(sb2f(vw0.x, 2), wv0, acc[2]);  acc[3]  = fmaf(sb2f(vw0.x, 3), wv0, acc[3]);
        acc[4]  = fmaf(sb2f(vw0.y, 0), wv0, acc[4]);  acc[5]  = fmaf(sb2f(vw0.y, 1), wv0, acc[5]);
        acc[6]  = fmaf(sb2f(vw0.y, 2), wv0, acc[6]);  acc[7]  = fmaf(sb2f(vw0.y, 3), wv0, acc[7]);
        acc[8]  = fmaf(sb2f(vw0.z, 0), wv0, acc[8]);  acc[9]  = fmaf(sb2f(vw0.z, 1), wv0, acc[9]);
        acc[10] = fmaf(sb2f(vw0.z, 2), wv0, acc[10]); acc[11] = fmaf(sb2f(vw0.z, 3), wv0, acc[11]);
        acc[12] = fmaf(sb2f(vw0.w, 0), wv0, acc[12]); acc[13] = fmaf(sb2f(vw0.w, 1), wv0, acc[13]);
        acc[14] = fmaf(sb2f(vw0.w, 2), wv0, acc[14]); acc[15] = fmaf(sb2f(vw0.w, 3), wv0, acc[15]);

        acc[0]  = fmaf(sb2f(vw1.x, 0), wv1, acc[0]);  acc[1]  = fmaf(sb2f(vw1.x, 1), wv1, acc[1]);
        acc[2]  = fmaf(sb2f(vw1.x, 2), wv1, acc[2]);  acc[3]  = fmaf(sb2f(vw1.x, 3), wv1, acc[3]);
        acc[4]  = fmaf(sb2f(vw1.y, 0), wv1, acc[4]);  acc[5]  = fmaf(sb2f(vw1.y, 1), wv1, acc[5]);
        acc[6]  = fmaf(sb2f(vw1.y, 2), wv1, acc[6]);  acc[7]  = fmaf(sb2f(vw1.y, 3), wv1, acc[7]);
        acc[8]  = fmaf(sb2f(vw1.z, 0), wv1, acc[8]);  acc[9]  = fmaf(sb2f(vw1.z, 1), wv1, acc[9]);
        acc[10] = fmaf(sb2f(vw1.z, 2), wv1, acc[10]); acc[11] = fmaf(sb2f(vw1.z, 3), wv1, acc[11]);
        acc[12] = fmaf(sb2f(vw1.w, 0), wv1, acc[12]); acc[13] = fmaf(sb2f(vw1.w, 1), wv1, acc[13]);
        acc[14] = fmaf(sb2f(vw1.w, 2), wv1, acc[14]); acc[15] = fmaf(sb2f(vw1.w, 3), wv1, acc[15]);
    }

    // reduce across edge slots (lanes differing in bits 3..5)
#pragma unroll
    for (int st = 8; st < 64; st <<= 1) {
        zacc += __shfl_xor(zacc, st);
#pragma unroll
        for (int j = 0; j < 16; ++j) acc[j] += __shfl_xor(acc[j], st);
    }

    if (eo == 0) {
        const float inv = 1.0f / zacc;
        float* op = out + (size_t)n * 128 + h * 16;
        *(float4*)(op)      = make_float4(acc[0]*inv,  acc[1]*inv,  acc[2]*inv,  acc[3]*inv);
        *(float4*)(op + 4)  = make_float4(acc[4]*inv,  acc[5]*inv,  acc[6]*inv,  acc[7]*inv);
        *(float4*)(op + 8)  = make_float4(acc[8]*inv,  acc[9]*inv,  acc[10]*inv, acc[11]*inv);
        *(float4*)(op + 12) = make_float4(acc[12]*inv, acc[13]*inv, acc[14]*inv, acc[15]*inv);
    }
}

extern "C" void kernel_launch(void* const* d_in, const int* in_sizes, int n_in,
                              void* d_out, int out_size, void* d_ws, size_t ws_size,
                              hipStream_t stream)
{
    const float* state = (const float*)d_in[0];
    const int*   src   = (const int*)d_in[1];
    const int*   dst   = (const int*)d_in[2];
    const float* WQ    = (const float*)d_in[3];
    const float* bQ    = (const float*)d_in[4];
    const float* WK    = (const float*)d_in[5];
    const float* bK    = (const float*)d_in[6];
    const float* WV    = (const float*)d_in[7];
    const float* bV    = (const float*)d_in[8];
    float* out = (float*)d_out;

    unsigned char*  Qbi = (unsigned char*)d_ws;                         // 6.4 MB
    unsigned char*  KVb = Qbi + (size_t)NNODES * 128;                   // 12.8 MB
    float*          scl = (float*)(KVb + (size_t)NNODES * 256);         // 800 KB
    unsigned short* WT  = (unsigned short*)(scl + (size_t)NNODES * 4);  // 96 KB
    int* pbuf  = (int*)(WT + 3 * 16384);                                // NB*BCAP*4B
    int* eidx  = pbuf + (size_t)NB * BCAP;
    int* gcur  = eidx + (size_t)NB * BCAP;                              // 256
    int2* offs2 = (int2*)(gcur + 256);                                  // 50000 int2

    hipMemsetAsync(gcur, 0, 256 * sizeof(int), stream);
    wt_p1<<<CWB + P1B, 256, 0, stream>>>(WQ, WK, WV, WT, src, dst, gcur, pbuf);
    proj_mfma<<<(NNODES + 63) / 64, 256, 0, stream>>>(state, WT, bQ, bK, bV, Qbi, KVb, scl);
    bucket_pass2<<<NB, 1024, 0, stream>>>(pbuf, gcur, eidx, offs2);
    aggregate_kernel<<<(NNODES + 3) / 4, 256, 0, stream>>>(eidx, offs2, Qbi, KVb, scl, out);
}